// Round 2
// baseline (702.395 us; speedup 1.0000x reference)
//
#include <hip/hip_runtime.h>
#include <stdint.h>

typedef __bf16   bf16x8 __attribute__((ext_vector_type(8)));
typedef float    f32x4  __attribute__((ext_vector_type(4)));
typedef uint16_t u16x8  __attribute__((ext_vector_type(8)));

__device__ __forceinline__ uint16_t f2bf(float f) {
  uint32_t b = __builtin_bit_cast(uint32_t, f);
  b += 0x7fffu + ((b >> 16) & 1u);
  return (uint16_t)(b >> 16);
}
__device__ __forceinline__ float bf2f(uint16_t u) {
  return __builtin_bit_cast(float, ((uint32_t)u) << 16);
}
// load 8 contiguous fp32, round to bf16x8 (for fused cast during LDS staging)
__device__ __forceinline__ u16x8 ldcvt8(const float* __restrict__ p) {
  f32x4 lo = *(const f32x4*)p;
  f32x4 hi = *(const f32x4*)(p + 4);
  u16x8 o;
  o[0] = f2bf(lo[0]); o[1] = f2bf(lo[1]); o[2] = f2bf(lo[2]); o[3] = f2bf(lo[3]);
  o[4] = f2bf(hi[0]); o[5] = f2bf(hi[1]); o[6] = f2bf(hi[2]); o[7] = f2bf(hi[3]);
  return o;
}

// address-space-qualified typedefs for global_load_lds
typedef const __attribute__((address_space(1))) uint32_t cga_u32;
typedef __attribute__((address_space(3))) uint32_t lds_u32;
__device__ __forceinline__ void gload16(const uint16_t* g, uint16_t* l) {
  __builtin_amdgcn_global_load_lds((cga_u32*)g, (lds_u32*)l, 16, 0, 0);
}

// ---------------- fp32 -> bf16 cast (memory-bound, vectorized) ----------------
__global__ __launch_bounds__(256) void cast_kernel(const float* __restrict__ in,
                                                   uint16_t* __restrict__ out, int n8) {
  int i = blockIdx.x * 256 + threadIdx.x;
  if (i >= n8) return;
  u16x8 o = ldcvt8(in + (size_t)i * 8);
  *(u16x8*)(out + (size_t)i * 8) = o;
}

// ---------------- copy both caches (input caches -> output regions) ----------------
__global__ __launch_bounds__(256) void copy2_kernel(const float* __restrict__ a, float* __restrict__ da,
                                                    const float* __restrict__ b, float* __restrict__ db,
                                                    int n4) {
  int i = blockIdx.x * 256 + threadIdx.x;
  if (i >= n4) return;
  *(f32x4*)(da + (size_t)i * 4) = *(const f32x4*)(a + (size_t)i * 4);
  *(f32x4*)(db + (size_t)i * 4) = *(const f32x4*)(b + (size_t)i * 4);
}

// ---------------- bf16 NT GEMM, m97 structure ----------------
template <int OUT_BF16>
__global__ __launch_bounds__(256) void gemm_nt_bf16(const uint16_t* __restrict__ A,
                                                    const uint16_t* __restrict__ B,
                                                    void* __restrict__ Cout,
                                                    int M, int N, int K) {
  __shared__ __align__(16) uint16_t As[128 * 32];
  __shared__ __align__(16) uint16_t Bs[128 * 32];
  const int tid = threadIdx.x;
  const int lane = tid & 63, wave = tid >> 6;
  const int l16 = lane & 15, quad = lane >> 4;
  const int wm = (wave & 1) << 6, wn = (wave >> 1) << 6;
  const int bm = blockIdx.y, bn = blockIdx.x;

  f32x4 acc[4][4] = {};

  const int srow = wave * 16 + (lane >> 2);
  const int schunk = lane & 3;
  const uint16_t* Ag = A + (size_t)(bm * 128 + srow) * K + schunk * 8;
  const uint16_t* Bg = B + (size_t)(bn * 128 + srow) * K + schunk * 8;
  const size_t rs64 = (size_t)64 * K;
  uint16_t* AsD0 = &As[srow * 32 + schunk * 8];
  uint16_t* AsD1 = AsD0 + 64 * 32;
  uint16_t* BsD0 = &Bs[srow * 32 + schunk * 8];
  uint16_t* BsD1 = BsD0 + 64 * 32;

  for (int k0 = 0; k0 < K; k0 += 32) {
    gload16(Ag, AsD0);
    gload16(Ag + rs64, AsD1);
    gload16(Bg, BsD0);
    gload16(Bg + rs64, BsD1);
    Ag += 32; Bg += 32;
    __syncthreads();
    bf16x8 af[4], bfr[4];
#pragma unroll
    for (int i = 0; i < 4; i++) {
      af[i]  = __builtin_bit_cast(bf16x8, *(const u16x8*)&As[(wm + i * 16 + l16) * 32 + quad * 8]);
      bfr[i] = __builtin_bit_cast(bf16x8, *(const u16x8*)&Bs[(wn + i * 16 + l16) * 32 + quad * 8]);
    }
#pragma unroll
    for (int i = 0; i < 4; i++)
#pragma unroll
      for (int j = 0; j < 4; j++)
        acc[i][j] = __builtin_amdgcn_mfma_f32_16x16x32_bf16(af[i], bfr[j], acc[i][j], 0, 0, 0);
    __syncthreads();
  }

  const int row0 = bm * 128 + wm + quad * 4;
  const int col0 = bn * 128 + wn + l16;
#pragma unroll
  for (int i = 0; i < 4; i++)
#pragma unroll
    for (int j = 0; j < 4; j++)
#pragma unroll
      for (int r = 0; r < 4; r++) {
        size_t idx = (size_t)(row0 + i * 16 + r) * N + (col0 + j * 16);
        if constexpr (OUT_BF16) ((uint16_t*)Cout)[idx] = f2bf(acc[i][j][r]);
        else                    ((float*)Cout)[idx]    = acc[i][j][r];
      }
}

// ---------------- fallback NT GEMM (fused fp32 cast, reg-staged) ----------------
template <int A_BF16, int OUT_BF16>
__global__ __launch_bounds__(256) void gemm_bt(const void* __restrict__ Ap,
                                               const float* __restrict__ B,
                                               void* __restrict__ Cout, int M, int N, int K) {
  constexpr int PAD = 40;
  __shared__ __align__(16) uint16_t As[128 * PAD];
  __shared__ __align__(16) uint16_t Bs[128 * PAD];
  const int tid = threadIdx.x;
  const int lane = tid & 63, wave = tid >> 6;
  const int l16 = lane & 15, quad = lane >> 4;
  const int wm = (wave & 1) << 6, wn = (wave >> 1) << 6;
  const int bm = blockIdx.y, bn = blockIdx.x;

  f32x4 acc[4][4] = {};

  const int srow = tid >> 2;
  const int scol = (tid & 3) << 3;
  const size_t aoff = (size_t)(bm * 128 + srow) * K + scol;
  const uint16_t* Agh = (const uint16_t*)Ap + aoff;
  const float*    Agf = (const float*)Ap + aoff;
  const float*    Bg  = B + (size_t)(bn * 128 + srow) * K + scol;
  const size_t rstride = (size_t)64 * K;

  for (int k0 = 0; k0 < K; k0 += 32) {
    u16x8 a0, a1;
    if constexpr (A_BF16) {
      a0 = *(const u16x8*)Agh;
      a1 = *(const u16x8*)(Agh + rstride);
      Agh += 32;
    } else {
      a0 = ldcvt8(Agf);
      a1 = ldcvt8(Agf + rstride);
      Agf += 32;
    }
    u16x8 b0 = ldcvt8(Bg);
    u16x8 b1 = ldcvt8(Bg + rstride);
    Bg += 32;
    __syncthreads();
    *(u16x8*)&As[srow * PAD + scol] = a0;
    *(u16x8*)&As[(srow + 64) * PAD + scol] = a1;
    *(u16x8*)&Bs[srow * PAD + scol] = b0;
    *(u16x8*)&Bs[(srow + 64) * PAD + scol] = b1;
    __syncthreads();
    bf16x8 af[4], bfr[4];
#pragma unroll
    for (int i = 0; i < 4; i++) {
      af[i]  = __builtin_bit_cast(bf16x8, *(const u16x8*)&As[(wm + i * 16 + l16) * PAD + quad * 8]);
      bfr[i] = __builtin_bit_cast(bf16x8, *(const u16x8*)&Bs[(wn + i * 16 + l16) * PAD + quad * 8]);
    }
#pragma unroll
    for (int i = 0; i < 4; i++)
#pragma unroll
      for (int j = 0; j < 4; j++)
        acc[i][j] = __builtin_amdgcn_mfma_f32_16x16x32_bf16(af[i], bfr[j], acc[i][j], 0, 0, 0);
  }

  const int row0 = bm * 128 + wm + quad * 4;
  const int col0 = bn * 128 + wn + l16;
#pragma unroll
  for (int i = 0; i < 4; i++)
#pragma unroll
    for (int j = 0; j < 4; j++)
#pragma unroll
      for (int r = 0; r < 4; r++) {
        size_t idx = (size_t)(row0 + i * 16 + r) * N + (col0 + j * 16);
        if constexpr (OUT_BF16) ((uint16_t*)Cout)[idx] = f2bf(acc[i][j][r]);
        else                    ((float*)Cout)[idx]    = acc[i][j][r];
      }
}

// ---------------- RoPE + cache scatter + attention-buffer emit ----------------
__global__ __launch_bounds__(256) void rope_kernel(const uint16_t* __restrict__ xqkv,
    const float* __restrict__ cosf, const float* __restrict__ sinf,
    const int* __restrict__ pos,
    uint16_t* __restrict__ qb, uint16_t* __restrict__ kb, uint16_t* __restrict__ vb,
    float* __restrict__ ck, float* __restrict__ cv) {
  const int s = blockIdx.x;
  const int e0 = (blockIdx.y * 256 + threadIdx.x) * 8;
  const int head = e0 >> 7;
  const int d0 = e0 & 127;
  u16x8 u = *(const u16x8*)(xqkv + (size_t)s * 6144 + e0);
  float x[8];
#pragma unroll
  for (int j = 0; j < 8; j++) x[j] = bf2f(u[j]);

  if (head < 40) {
    const int i0 = d0 >> 1;
    f32x4 c4 = *(const f32x4*)(cosf + (size_t)s * 64 + i0);
    f32x4 s4 = *(const f32x4*)(sinf + (size_t)s * 64 + i0);
    float o[8];
#pragma unroll
    for (int kk = 0; kk < 4; kk++) {
      float x1 = x[2 * kk], x2 = x[2 * kk + 1];
      o[2 * kk]     = x1 * c4[kk] - x2 * s4[kk];
      o[2 * kk + 1] = x1 * s4[kk] + x2 * c4[kk];
    }
    u16x8 ob;
#pragma unroll
    for (int j = 0; j < 8; j++) ob[j] = f2bf(o[j]);
    if (head < 32) {
      *(u16x8*)(qb + (size_t)s * 4096 + head * 128 + d0) = ob;
    } else {
      int kvh = head - 32;
      *(u16x8*)(kb + ((size_t)kvh * 2048 + s) * 128 + d0) = ob;
      int p = pos[s];
      if ((unsigned)p < 4096u) {
        float* dst = ck + ((size_t)p * 8 + kvh) * 128 + d0;
#pragma unroll
        for (int j = 0; j < 8; j++) dst[j] = o[j];
      }
    }
  } else {
    int kvh = head - 40;
    *(u16x8*)(vb + ((size_t)kvh * 2048 + s) * 128 + d0) = u;
    int p = pos[s];
    if ((unsigned)p < 4096u) {
      float* dst = cv + ((size_t)p * 8 + kvh) * 128 + d0;
#pragma unroll
      for (int j = 0; j < 8; j++) dst[j] = x[j];
    }
  }
}

// ---------------- V transpose per kv head: [8][2048][128] -> [8][128][2048] ----------------
__global__ __launch_bounds__(256) void vtrans_kernel(const uint16_t* __restrict__ vb,
                                                     uint16_t* __restrict__ vt) {
  __shared__ __align__(16) uint16_t t[32 * 72];
  const int h = blockIdx.z;
  const int s0 = blockIdx.x * 64, d0 = blockIdx.y * 32;
  const uint16_t* in = vb + (size_t)h * 2048 * 128;
  uint16_t* out = vt + (size_t)h * 128 * 2048;
  const int tid = threadIdx.x;
  {
    int r = tid >> 2, c8 = (tid & 3) * 8;
    u16x8 v = *(const u16x8*)(in + (size_t)(s0 + r) * 128 + d0 + c8);
#pragma unroll
    for (int j = 0; j < 8; j++) t[(c8 + j) * 72 + r] = v[j];
  }
  __syncthreads();
  {
    int r = tid >> 3, c8 = (tid & 7) * 8;
    u16x8 v = *(const u16x8*)&t[r * 72 + c8];
    *(u16x8*)(out + (size_t)(d0 + r) * 2048 + s0 + c8) = v;
  }
}

// ---------------- flash attention v2 ----------------
// Changes vs v1: no Qs LDS (direct global Q-frag loads); XOR-swizzled Ks/Vts/Ps
// (T2: byte ^= (row&7)<<4, no pads -> 40KB LDS, conflict-free ds_read_b128);
// async-STAGE prefetch of next K/V chunk into regs (T14); setprio around MFMA (T5);
// reversed qtile dispatch order; wave-uniform causal skip on diagonal chunk.
__global__ __launch_bounds__(256) void flash_kernel(const uint16_t* __restrict__ Qb,
    const uint16_t* __restrict__ Kb, const uint16_t* __restrict__ Vtb,
    uint16_t* __restrict__ Ob) {
  // Ks: 64 rows x 128 u16 (256B rows); Vts: 128 rows x 64 u16 (128B); Ps: per-wave 16 x 64 u16
  __shared__ __align__(16) uint16_t Ks[64 * 128];
  __shared__ __align__(16) uint16_t Vts[128 * 64];
  __shared__ __align__(16) uint16_t Ps[4][16 * 64];
  const int tid = threadIdx.x;
  const int lane = tid & 63, wave = tid >> 6;
  const int l16 = lane & 15, quad = lane >> 4;
  const int qtile = 31 - blockIdx.x;       // reversed: heavy blocks dispatch first
  const int qb = qtile * 64;
  const int h = blockIdx.y, kvh = h >> 2;
  const uint16_t* Kg = Kb + (size_t)kvh * 2048 * 128;
  const uint16_t* Vg = Vtb + (size_t)kvh * 128 * 2048;

  // Q fragments direct from global (once): row qb+wave*16+l16, cols dc*32+quad*8
  bf16x8 qf[4];
  {
    const uint16_t* Qg = Qb + (size_t)(qb + wave * 16 + l16) * 4096 + h * 128 + quad * 8;
#pragma unroll
    for (int dc = 0; dc < 4; dc++)
      qf[dc] = __builtin_bit_cast(bf16x8, *(const u16x8*)(Qg + dc * 32));
  }

  // staging coordinates (per thread, fixed): K: 4x(row, colbyte); V: 4x(row, colbyte)
  // K iter i: c = tid + i*256 -> r = c>>4, colb = (c&15)*16
  // V iter i: c = tid + i*256 -> r = c>>3, colb = (c&7)*16
  u16x8 kreg[4], vreg[4];
  const int krr = tid >> 4, kcb = (tid & 15) * 16;          // K row base (step 16/iter)
  const int vrr = tid >> 3, vcb = (tid & 7) * 16;           // V row base (step 32/iter)

  f32x4 oacc[8] = {};
  float m_run[4], l_run[4];
#pragma unroll
  for (int r = 0; r < 4; r++) { m_run[r] = -1e30f; l_run[r] = 0.f; }
  const float scale = 0.08838834764831845f;
  const int nch = qtile + 1;
  const int qmax = qb + wave * 16 + 15;    // wave's max q row (for causal block-skip)

  // prefetch chunk 0
#pragma unroll
  for (int i = 0; i < 4; i++)
    kreg[i] = *(const u16x8*)(Kg + (size_t)(krr + i * 16) * 128 + kcb / 2);
#pragma unroll
  for (int i = 0; i < 4; i++)
    vreg[i] = *(const u16x8*)(Vg + (size_t)(vrr + i * 32) * 2048 + vcb / 2);

  for (int ch = 0; ch < nch; ch++) {
    const int cb = ch * 64;
    // write staged regs -> swizzled LDS
#pragma unroll
    for (int i = 0; i < 4; i++) {
      int r = krr + i * 16;
      *(u16x8*)((char*)Ks + r * 256 + (kcb ^ ((r & 7) << 4))) = kreg[i];
    }
#pragma unroll
    for (int i = 0; i < 4; i++) {
      int r = vrr + i * 32;
      *(u16x8*)((char*)Vts + r * 128 + (vcb ^ ((r & 7) << 4))) = vreg[i];
    }
    __syncthreads();

    // issue next chunk's global loads (hidden under compute)
    if (ch + 1 < nch) {
      const int nb = cb + 64;
#pragma unroll
      for (int i = 0; i < 4; i++)
        kreg[i] = *(const u16x8*)(Kg + (size_t)(nb + krr + i * 16) * 128 + kcb / 2);
#pragma unroll
      for (int i = 0; i < 4; i++)
        vreg[i] = *(const u16x8*)(Vg + (size_t)(vrr + i * 32) * 2048 + nb + vcb / 2);
    }

    // QK^T: S[16q x 64k] per wave; skip fully-masked 16-key blocks (diagonal chunk)
    f32x4 sacc[4] = {};
    __builtin_amdgcn_s_setprio(1);
#pragma unroll
    for (int ni = 0; ni < 4; ni++) {
      if (cb + ni * 16 <= qmax) {
#pragma unroll
        for (int dc = 0; dc < 4; dc++) {
          int r = ni * 16 + l16;
          bf16x8 kf = __builtin_bit_cast(bf16x8,
              *(const u16x8*)((const char*)Ks + r * 256 + ((dc * 64 + quad * 16) ^ ((r & 7) << 4))));
          sacc[ni] = __builtin_amdgcn_mfma_f32_16x16x32_bf16(qf[dc], kf, sacc[ni], 0, 0, 0);
        }
      }
    }
    __builtin_amdgcn_s_setprio(0);

    // online softmax; S row = quad*4+reg, col = cb + ni*16 + l16
    float p[4][4], alpha[4];
#pragma unroll
    for (int reg = 0; reg < 4; reg++) {
      const int q = qb + wave * 16 + quad * 4 + reg;
      float mx = -1e30f;
#pragma unroll
      for (int ni = 0; ni < 4; ni++) {
        float sv = sacc[ni][reg] * scale;
        if (cb + ni * 16 + l16 > q) sv = -1e30f;
        p[ni][reg] = sv;
        mx = fmaxf(mx, sv);
      }
#pragma unroll
      for (int off = 8; off >= 1; off >>= 1)
        mx = fmaxf(mx, __shfl_xor(mx, off, 64));
      float mn = fmaxf(m_run[reg], mx);
      alpha[reg] = __expf(m_run[reg] - mn);
      m_run[reg] = mn;
      float rs = 0.f;
#pragma unroll
      for (int ni = 0; ni < 4; ni++) {
        float e = __expf(p[ni][reg] - mn);
        p[ni][reg] = e;
        rs += e;
      }
#pragma unroll
      for (int off = 8; off >= 1; off >>= 1)
        rs += __shfl_xor(rs, off, 64);
      l_run[reg] = l_run[reg] * alpha[reg] + rs;
    }

#pragma unroll
    for (int dt = 0; dt < 8; dt++)
#pragma unroll
      for (int reg = 0; reg < 4; reg++)
        oacc[dt][reg] *= alpha[reg];

    // P: C-layout -> A-layout via per-wave swizzled LDS round-trip
    uint16_t* Pw = Ps[wave];
#pragma unroll
    for (int ni = 0; ni < 4; ni++)
#pragma unroll
      for (int reg = 0; reg < 4; reg++) {
        int r = quad * 4 + reg;
        *(uint16_t*)((char*)Pw + r * 128 + ((ni * 32 + l16 * 2) ^ ((r & 7) << 4))) =
            f2bf(p[ni][reg]);
      }

    // PV: skip fully-masked 32-key halves (diagonal chunk)
    __builtin_amdgcn_s_setprio(1);
#pragma unroll
    for (int kc = 0; kc < 2; kc++) {
      if (cb + kc * 32 <= qmax) {
        bf16x8 pf = __builtin_bit_cast(bf16x8,
            *(const u16x8*)((const char*)Pw + l16 * 128 + ((kc * 64 + quad * 16) ^ ((l16 & 7) << 4))));
#pragma unroll
        for (int dt = 0; dt < 8; dt++) {
          int r = dt * 16 + l16;
          bf16x8 vf = __builtin_bit_cast(bf16x8,
              *(const u16x8*)((const char*)Vts + r * 128 + ((kc * 64 + quad * 16) ^ ((r & 7) << 4))));
          oacc[dt] = __builtin_amdgcn_mfma_f32_16x16x32_bf16(pf, vf, oacc[dt], 0, 0, 0);
        }
      }
    }
    __builtin_amdgcn_s_setprio(0);

    __syncthreads();  // protect Ks/Vts before next chunk's LDS writes
  }

#pragma unroll
  for (int dt = 0; dt < 8; dt++)
#pragma unroll
    for (int reg = 0; reg < 4; reg++) {
      float o = oacc[dt][reg] / l_run[reg];
      int row = qb + wave * 16 + quad * 4 + reg;
      int col = h * 128 + dt * 16 + l16;
      Ob[(size_t)row * 4096 + col] = f2bf(o);
    }
}

extern "C" void kernel_launch(void* const* d_in, const int* in_sizes, int n_in,
                              void* d_out, int out_size, void* d_ws, size_t ws_size,
                              hipStream_t stream) {
  const float* x     = (const float*)d_in[0];
  const float* cosf  = (const float*)d_in[1];
  const float* sinf  = (const float*)d_in[2];
  const int*   pos   = (const int*)d_in[3];
  const float* ck_in = (const float*)d_in[5];
  const float* cv_in = (const float*)d_in[6];
  const float* Wqkv  = (const float*)d_in[7];
  const float* Wo    = (const float*)d_in[8];

  float* out    = (float*)d_out;
  float* ck_out = out + (size_t)2048 * 4096;
  float* cv_out = ck_out + (size_t)4096 * 8 * 128;

  char* ws = (char*)d_ws;

  if (ws_size >= 104857600ull) {
    uint16_t* xqkv_bf = (uint16_t*)(ws);
    uint16_t* attn_bf = (uint16_t*)(ws);
    uint16_t* x_bf    = (uint16_t*)(ws + 25165824);
    uint16_t* q_bf    = (uint16_t*)(ws + 25165824);
    uint16_t* k_bf    = (uint16_t*)(ws + 41943040);
    uint16_t* v_bf    = (uint16_t*)(ws + 46137344);
    uint16_t* vt_bf   = (uint16_t*)(ws + 50331648);
    uint16_t* wq_bf   = (uint16_t*)(ws + 54525952);
    uint16_t* wo_bf   = (uint16_t*)(ws + 54525952);

    cast_kernel<<<4096, 256, 0, stream>>>(x, x_bf, 1048576);
    cast_kernel<<<12288, 256, 0, stream>>>(Wqkv, wq_bf, 3145728);

    gemm_nt_bf16<1><<<dim3(48, 16), 256, 0, stream>>>(x_bf, wq_bf, xqkv_bf, 2048, 6144, 4096);

    copy2_kernel<<<4096, 256, 0, stream>>>(ck_in, ck_out, cv_in, cv_out, 1048576);

    rope_kernel<<<dim3(2048, 3), 256, 0, stream>>>(xqkv_bf, cosf, sinf, pos,
                                                   q_bf, k_bf, v_bf, ck_out, cv_out);

    vtrans_kernel<<<dim3(32, 4, 8), 256, 0, stream>>>(v_bf, vt_bf);

    flash_kernel<<<dim3(32, 32), 256, 0, stream>>>(q_bf, k_bf, vt_bf, attn_bf);

    cast_kernel<<<8192, 256, 0, stream>>>(Wo, wo_bf, 2097152);

    gemm_nt_bf16<0><<<dim3(32, 16), 256, 0, stream>>>(attn_bf, wo_bf, out, 2048, 4096, 4096);
  } else {
    uint16_t* xqkv_bf = (uint16_t*)(ws);
    uint16_t* attn_bf = (uint16_t*)(ws);
    uint16_t* q_bf    = (uint16_t*)(ws + 25165824);
    uint16_t* k_bf    = (uint16_t*)(ws + 41943040);
    uint16_t* v_bf    = (uint16_t*)(ws + 46137344);
    uint16_t* vt_bf   = (uint16_t*)(ws + 50331648);

    gemm_bt<0, 1><<<dim3(48, 16), 256, 0, stream>>>(x, Wqkv, xqkv_bf, 2048, 6144, 4096);
    copy2_kernel<<<4096, 256, 0, stream>>>(ck_in, ck_out, cv_in, cv_out, 1048576);
    rope_kernel<<<dim3(2048, 3), 256, 0, stream>>>(xqkv_bf, cosf, sinf, pos,
                                                   q_bf, k_bf, v_bf, ck_out, cv_out);
    vtrans_kernel<<<dim3(32, 4, 8), 256, 0, stream>>>(v_bf, vt_bf);
    flash_kernel<<<dim3(32, 32), 256, 0, stream>>>(q_bf, k_bf, vt_bf, attn_bf);
    gemm_bt<1, 0><<<dim3(32, 16), 256, 0, stream>>>(attn_bf, Wo, out, 2048, 4096, 4096);
  }
}

// Round 3
// 614.629 us; speedup vs baseline: 1.1428x; 1.1428x over previous
//
#include <hip/hip_runtime.h>
#include <stdint.h>

typedef __bf16   bf16x8 __attribute__((ext_vector_type(8)));
typedef float    f32x4  __attribute__((ext_vector_type(4)));
typedef uint16_t u16x8  __attribute__((ext_vector_type(8)));

__device__ __forceinline__ uint16_t f2bf(float f) {
  uint32_t b = __builtin_bit_cast(uint32_t, f);
  b += 0x7fffu + ((b >> 16) & 1u);
  return (uint16_t)(b >> 16);
}
__device__ __forceinline__ float bf2f(uint16_t u) {
  return __builtin_bit_cast(float, ((uint32_t)u) << 16);
}
__device__ __forceinline__ u16x8 ldcvt8(const float* __restrict__ p) {
  f32x4 lo = *(const f32x4*)p;
  f32x4 hi = *(const f32x4*)(p + 4);
  u16x8 o;
  o[0] = f2bf(lo[0]); o[1] = f2bf(lo[1]); o[2] = f2bf(lo[2]); o[3] = f2bf(lo[3]);
  o[4] = f2bf(hi[0]); o[5] = f2bf(hi[1]); o[6] = f2bf(hi[2]); o[7] = f2bf(hi[3]);
  return o;
}

typedef const __attribute__((address_space(1))) uint32_t cga_u32;
typedef __attribute__((address_space(3))) uint32_t lds_u32;
__device__ __forceinline__ void gload16(const uint16_t* g, uint16_t* l) {
  __builtin_amdgcn_global_load_lds((cga_u32*)g, (lds_u32*)l, 16, 0, 0);
}

// ---------------- fp32 -> bf16 cast ----------------
__global__ __launch_bounds__(256) void cast_kernel(const float* __restrict__ in,
                                                   uint16_t* __restrict__ out, int n8) {
  int i = blockIdx.x * 256 + threadIdx.x;
  if (i >= n8) return;
  u16x8 o = ldcvt8(in + (size_t)i * 8);
  *(u16x8*)(out + (size_t)i * 8) = o;
}

// ---------------- copy both caches ----------------
__global__ __launch_bounds__(256) void copy2_kernel(const float* __restrict__ a, float* __restrict__ da,
                                                    const float* __restrict__ b, float* __restrict__ db,
                                                    int n4) {
  int i = blockIdx.x * 256 + threadIdx.x;
  if (i >= n4) return;
  *(f32x4*)(da + (size_t)i * 4) = *(const f32x4*)(a + (size_t)i * 4);
  *(f32x4*)(db + (size_t)i * 4) = *(const f32x4*)(b + (size_t)i * 4);
}

// ---------------- bf16 NT GEMM, m97 structure ----------------
template <int OUT_BF16>
__global__ __launch_bounds__(256) void gemm_nt_bf16(const uint16_t* __restrict__ A,
                                                    const uint16_t* __restrict__ B,
                                                    void* __restrict__ Cout,
                                                    int M, int N, int K) {
  __shared__ __align__(16) uint16_t As[128 * 32];
  __shared__ __align__(16) uint16_t Bs[128 * 32];
  const int tid = threadIdx.x;
  const int lane = tid & 63, wave = tid >> 6;
  const int l16 = lane & 15, quad = lane >> 4;
  const int wm = (wave & 1) << 6, wn = (wave >> 1) << 6;
  const int bm = blockIdx.y, bn = blockIdx.x;

  f32x4 acc[4][4] = {};

  const int srow = wave * 16 + (lane >> 2);
  const int schunk = lane & 3;
  const uint16_t* Ag = A + (size_t)(bm * 128 + srow) * K + schunk * 8;
  const uint16_t* Bg = B + (size_t)(bn * 128 + srow) * K + schunk * 8;
  const size_t rs64 = (size_t)64 * K;
  uint16_t* AsD0 = &As[srow * 32 + schunk * 8];
  uint16_t* AsD1 = AsD0 + 64 * 32;
  uint16_t* BsD0 = &Bs[srow * 32 + schunk * 8];
  uint16_t* BsD1 = BsD0 + 64 * 32;

  for (int k0 = 0; k0 < K; k0 += 32) {
    gload16(Ag, AsD0);
    gload16(Ag + rs64, AsD1);
    gload16(Bg, BsD0);
    gload16(Bg + rs64, BsD1);
    Ag += 32; Bg += 32;
    __syncthreads();
    bf16x8 af[4], bfr[4];
#pragma unroll
    for (int i = 0; i < 4; i++) {
      af[i]  = __builtin_bit_cast(bf16x8, *(const u16x8*)&As[(wm + i * 16 + l16) * 32 + quad * 8]);
      bfr[i] = __builtin_bit_cast(bf16x8, *(const u16x8*)&Bs[(wn + i * 16 + l16) * 32 + quad * 8]);
    }
#pragma unroll
    for (int i = 0; i < 4; i++)
#pragma unroll
      for (int j = 0; j < 4; j++)
        acc[i][j] = __builtin_amdgcn_mfma_f32_16x16x32_bf16(af[i], bfr[j], acc[i][j], 0, 0, 0);
    __syncthreads();
  }

  const int row0 = bm * 128 + wm + quad * 4;
  const int col0 = bn * 128 + wn + l16;
#pragma unroll
  for (int i = 0; i < 4; i++)
#pragma unroll
    for (int j = 0; j < 4; j++)
#pragma unroll
      for (int r = 0; r < 4; r++) {
        size_t idx = (size_t)(row0 + i * 16 + r) * N + (col0 + j * 16);
        if constexpr (OUT_BF16) ((uint16_t*)Cout)[idx] = f2bf(acc[i][j][r]);
        else                    ((float*)Cout)[idx]    = acc[i][j][r];
      }
}

// ---------------- fallback NT GEMM (fused fp32 cast, reg-staged) ----------------
template <int A_BF16, int OUT_BF16>
__global__ __launch_bounds__(256) void gemm_bt(const void* __restrict__ Ap,
                                               const float* __restrict__ B,
                                               void* __restrict__ Cout, int M, int N, int K) {
  constexpr int PAD = 40;
  __shared__ __align__(16) uint16_t As[128 * PAD];
  __shared__ __align__(16) uint16_t Bs[128 * PAD];
  const int tid = threadIdx.x;
  const int lane = tid & 63, wave = tid >> 6;
  const int l16 = lane & 15, quad = lane >> 4;
  const int wm = (wave & 1) << 6, wn = (wave >> 1) << 6;
  const int bm = blockIdx.y, bn = blockIdx.x;

  f32x4 acc[4][4] = {};

  const int srow = tid >> 2;
  const int scol = (tid & 3) << 3;
  const size_t aoff = (size_t)(bm * 128 + srow) * K + scol;
  const uint16_t* Agh = (const uint16_t*)Ap + aoff;
  const float*    Agf = (const float*)Ap + aoff;
  const float*    Bg  = B + (size_t)(bn * 128 + srow) * K + scol;
  const size_t rstride = (size_t)64 * K;

  for (int k0 = 0; k0 < K; k0 += 32) {
    u16x8 a0, a1;
    if constexpr (A_BF16) {
      a0 = *(const u16x8*)Agh;
      a1 = *(const u16x8*)(Agh + rstride);
      Agh += 32;
    } else {
      a0 = ldcvt8(Agf);
      a1 = ldcvt8(Agf + rstride);
      Agf += 32;
    }
    u16x8 b0 = ldcvt8(Bg);
    u16x8 b1 = ldcvt8(Bg + rstride);
    Bg += 32;
    __syncthreads();
    *(u16x8*)&As[srow * PAD + scol] = a0;
    *(u16x8*)&As[(srow + 64) * PAD + scol] = a1;
    *(u16x8*)&Bs[srow * PAD + scol] = b0;
    *(u16x8*)&Bs[(srow + 64) * PAD + scol] = b1;
    __syncthreads();
    bf16x8 af[4], bfr[4];
#pragma unroll
    for (int i = 0; i < 4; i++) {
      af[i]  = __builtin_bit_cast(bf16x8, *(const u16x8*)&As[(wm + i * 16 + l16) * PAD + quad * 8]);
      bfr[i] = __builtin_bit_cast(bf16x8, *(const u16x8*)&Bs[(wn + i * 16 + l16) * PAD + quad * 8]);
    }
#pragma unroll
    for (int i = 0; i < 4; i++)
#pragma unroll
      for (int j = 0; j < 4; j++)
        acc[i][j] = __builtin_amdgcn_mfma_f32_16x16x32_bf16(af[i], bfr[j], acc[i][j], 0, 0, 0);
  }

  const int row0 = bm * 128 + wm + quad * 4;
  const int col0 = bn * 128 + wn + l16;
#pragma unroll
  for (int i = 0; i < 4; i++)
#pragma unroll
    for (int j = 0; j < 4; j++)
#pragma unroll
      for (int r = 0; r < 4; r++) {
        size_t idx = (size_t)(row0 + i * 16 + r) * N + (col0 + j * 16);
        if constexpr (OUT_BF16) ((uint16_t*)Cout)[idx] = f2bf(acc[i][j][r]);
        else                    ((float*)Cout)[idx]    = acc[i][j][r];
      }
}

// ---------------- RoPE + cache scatter + attention-buffer emit ----------------
// Q heads are pre-scaled by 128^-0.5 * log2(e) so flash softmax runs in base-2 domain
// with no per-score multiply (q_bf is consumed ONLY by flash_kernel).
__global__ __launch_bounds__(256) void rope_kernel(const uint16_t* __restrict__ xqkv,
    const float* __restrict__ cosf, const float* __restrict__ sinf,
    const int* __restrict__ pos,
    uint16_t* __restrict__ qb, uint16_t* __restrict__ kb, uint16_t* __restrict__ vb,
    float* __restrict__ ck, float* __restrict__ cv) {
  const float QS = 0.12751743f;  // 128^-0.5 * log2(e)
  const int s = blockIdx.x;
  const int e0 = (blockIdx.y * 256 + threadIdx.x) * 8;
  const int head = e0 >> 7;
  const int d0 = e0 & 127;
  u16x8 u = *(const u16x8*)(xqkv + (size_t)s * 6144 + e0);
  float x[8];
#pragma unroll
  for (int j = 0; j < 8; j++) x[j] = bf2f(u[j]);

  if (head < 40) {
    const int i0 = d0 >> 1;
    f32x4 c4 = *(const f32x4*)(cosf + (size_t)s * 64 + i0);
    f32x4 s4 = *(const f32x4*)(sinf + (size_t)s * 64 + i0);
    float o[8];
#pragma unroll
    for (int kk = 0; kk < 4; kk++) {
      float x1 = x[2 * kk], x2 = x[2 * kk + 1];
      o[2 * kk]     = x1 * c4[kk] - x2 * s4[kk];
      o[2 * kk + 1] = x1 * s4[kk] + x2 * c4[kk];
    }
    if (head < 32) {
      u16x8 ob;
#pragma unroll
      for (int j = 0; j < 8; j++) ob[j] = f2bf(o[j] * QS);
      *(u16x8*)(qb + (size_t)s * 4096 + head * 128 + d0) = ob;
    } else {
      u16x8 ob;
#pragma unroll
      for (int j = 0; j < 8; j++) ob[j] = f2bf(o[j]);
      int kvh = head - 32;
      *(u16x8*)(kb + ((size_t)kvh * 2048 + s) * 128 + d0) = ob;
      int p = pos[s];
      if ((unsigned)p < 4096u) {
        float* dst = ck + ((size_t)p * 8 + kvh) * 128 + d0;
#pragma unroll
        for (int j = 0; j < 8; j++) dst[j] = o[j];
      }
    }
  } else {
    int kvh = head - 40;
    *(u16x8*)(vb + ((size_t)kvh * 2048 + s) * 128 + d0) = u;
    int p = pos[s];
    if ((unsigned)p < 4096u) {
      float* dst = cv + ((size_t)p * 8 + kvh) * 128 + d0;
#pragma unroll
      for (int j = 0; j < 8; j++) dst[j] = x[j];
    }
  }
}

// ---------------- V transpose per kv head ----------------
__global__ __launch_bounds__(256) void vtrans_kernel(const uint16_t* __restrict__ vb,
                                                     uint16_t* __restrict__ vt) {
  __shared__ __align__(16) uint16_t t[32 * 72];
  const int h = blockIdx.z;
  const int s0 = blockIdx.x * 64, d0 = blockIdx.y * 32;
  const uint16_t* in = vb + (size_t)h * 2048 * 128;
  uint16_t* out = vt + (size_t)h * 128 * 2048;
  const int tid = threadIdx.x;
  {
    int r = tid >> 2, c8 = (tid & 3) * 8;
    u16x8 v = *(const u16x8*)(in + (size_t)(s0 + r) * 128 + d0 + c8);
#pragma unroll
    for (int j = 0; j < 8; j++) t[(c8 + j) * 72 + r] = v[j];
  }
  __syncthreads();
  {
    int r = tid >> 3, c8 = (tid & 7) * 8;
    u16x8 v = *(const u16x8*)&t[r * 72 + c8];
    *(u16x8*)(out + (size_t)(d0 + r) * 2048 + s0 + c8) = v;
  }
}

// ---------------- flash attention v3 ----------------
// v3: qtile PAIRING for uniform block duration — pair p handles qtiles {31-p, p},
// (32-p)+(p+1)=33 chunks for every block -> 512 uniform blocks, no occupancy decay.
// Q pre-scaled at rope time; softmax in base-2 domain (exp2, no scale multiply).
__global__ __launch_bounds__(256) void flash_kernel(const uint16_t* __restrict__ Qb,
    const uint16_t* __restrict__ Kb, const uint16_t* __restrict__ Vtb,
    uint16_t* __restrict__ Ob) {
  __shared__ __align__(16) uint16_t Ks[64 * 128];
  __shared__ __align__(16) uint16_t Vts[128 * 64];
  __shared__ __align__(16) uint16_t Ps[4][16 * 64];
  const int tid = threadIdx.x;
  const int lane = tid & 63, wave = tid >> 6;
  const int l16 = lane & 15, quad = lane >> 4;
  const int h = blockIdx.y, kvh = h >> 2;
  const uint16_t* Kg = Kb + (size_t)kvh * 2048 * 128;
  const uint16_t* Vg = Vtb + (size_t)kvh * 128 * 2048;

  u16x8 kreg[4], vreg[4];
  const int krr = tid >> 4, kcb = (tid & 15) * 16;
  const int vrr = tid >> 3, vcb = (tid & 7) * 16;

  for (int ph = 0; ph < 2; ph++) {
    const int qtile = ph ? (int)blockIdx.x : 31 - (int)blockIdx.x;  // heavy phase first
    const int qb = qtile * 64;
    const int nch = qtile + 1;
    const int qmax = qb + wave * 16 + 15;

    // Q fragments direct from global
    bf16x8 qf[4];
    {
      const uint16_t* Qg = Qb + (size_t)(qb + wave * 16 + l16) * 4096 + h * 128 + quad * 8;
#pragma unroll
      for (int dc = 0; dc < 4; dc++)
        qf[dc] = __builtin_bit_cast(bf16x8, *(const u16x8*)(Qg + dc * 32));
    }

    f32x4 oacc[8] = {};
    float m_run[4], l_run[4];
#pragma unroll
    for (int r = 0; r < 4; r++) { m_run[r] = -1e30f; l_run[r] = 0.f; }

    // prefetch chunk 0
#pragma unroll
    for (int i = 0; i < 4; i++)
      kreg[i] = *(const u16x8*)(Kg + (size_t)(krr + i * 16) * 128 + kcb / 2);
#pragma unroll
    for (int i = 0; i < 4; i++)
      vreg[i] = *(const u16x8*)(Vg + (size_t)(vrr + i * 32) * 2048 + vcb / 2);

    for (int ch = 0; ch < nch; ch++) {
      const int cb = ch * 64;
      // write staged regs -> swizzled LDS
#pragma unroll
      for (int i = 0; i < 4; i++) {
        int r = krr + i * 16;
        *(u16x8*)((char*)Ks + r * 256 + (kcb ^ ((r & 7) << 4))) = kreg[i];
      }
#pragma unroll
      for (int i = 0; i < 4; i++) {
        int r = vrr + i * 32;
        *(u16x8*)((char*)Vts + r * 128 + (vcb ^ ((r & 7) << 4))) = vreg[i];
      }
      __syncthreads();

      // issue next chunk's global loads (hidden under compute)
      if (ch + 1 < nch) {
        const int nb = cb + 64;
#pragma unroll
        for (int i = 0; i < 4; i++)
          kreg[i] = *(const u16x8*)(Kg + (size_t)(nb + krr + i * 16) * 128 + kcb / 2);
#pragma unroll
        for (int i = 0; i < 4; i++)
          vreg[i] = *(const u16x8*)(Vg + (size_t)(vrr + i * 32) * 2048 + nb + vcb / 2);
      }

      // QK^T (Q pre-scaled); skip fully-masked 16-key blocks
      f32x4 sacc[4] = {};
      __builtin_amdgcn_s_setprio(1);
#pragma unroll
      for (int ni = 0; ni < 4; ni++) {
        if (cb + ni * 16 <= qmax) {
#pragma unroll
          for (int dc = 0; dc < 4; dc++) {
            int r = ni * 16 + l16;
            bf16x8 kf = __builtin_bit_cast(bf16x8,
                *(const u16x8*)((const char*)Ks + r * 256 + ((dc * 64 + quad * 16) ^ ((r & 7) << 4))));
            sacc[ni] = __builtin_amdgcn_mfma_f32_16x16x32_bf16(qf[dc], kf, sacc[ni], 0, 0, 0);
          }
        }
      }
      __builtin_amdgcn_s_setprio(0);

      // online softmax (base-2 domain)
      float p[4][4], alpha[4];
#pragma unroll
      for (int reg = 0; reg < 4; reg++) {
        const int q = qb + wave * 16 + quad * 4 + reg;
        float mx = -1e30f;
#pragma unroll
        for (int ni = 0; ni < 4; ni++) {
          float sv = sacc[ni][reg];
          if (cb + ni * 16 + l16 > q) sv = -1e30f;
          p[ni][reg] = sv;
          mx = fmaxf(mx, sv);
        }
#pragma unroll
        for (int off = 8; off >= 1; off >>= 1)
          mx = fmaxf(mx, __shfl_xor(mx, off, 64));
        float mn = fmaxf(m_run[reg], mx);
        alpha[reg] = __builtin_amdgcn_exp2f(m_run[reg] - mn);
        m_run[reg] = mn;
        float rs = 0.f;
#pragma unroll
        for (int ni = 0; ni < 4; ni++) {
          float e = __builtin_amdgcn_exp2f(p[ni][reg] - mn);
          p[ni][reg] = e;
          rs += e;
        }
#pragma unroll
        for (int off = 8; off >= 1; off >>= 1)
          rs += __shfl_xor(rs, off, 64);
        l_run[reg] = l_run[reg] * alpha[reg] + rs;
      }

#pragma unroll
      for (int dt = 0; dt < 8; dt++)
#pragma unroll
        for (int reg = 0; reg < 4; reg++)
          oacc[dt][reg] *= alpha[reg];

      // P: C-layout -> A-layout via per-wave swizzled LDS round-trip
      uint16_t* Pw = Ps[wave];
#pragma unroll
      for (int ni = 0; ni < 4; ni++)
#pragma unroll
        for (int reg = 0; reg < 4; reg++) {
          int r = quad * 4 + reg;
          *(uint16_t*)((char*)Pw + r * 128 + ((ni * 32 + l16 * 2) ^ ((r & 7) << 4))) =
              f2bf(p[ni][reg]);
        }

      // PV; skip fully-masked 32-key halves
      __builtin_amdgcn_s_setprio(1);
#pragma unroll
      for (int kc = 0; kc < 2; kc++) {
        if (cb + kc * 32 <= qmax) {
          bf16x8 pf = __builtin_bit_cast(bf16x8,
              *(const u16x8*)((const char*)Pw + l16 * 128 + ((kc * 64 + quad * 16) ^ ((l16 & 7) << 4))));
#pragma unroll
          for (int dt = 0; dt < 8; dt++) {
            int r = dt * 16 + l16;
            bf16x8 vf = __builtin_bit_cast(bf16x8,
                *(const u16x8*)((const char*)Vts + r * 128 + ((kc * 64 + quad * 16) ^ ((r & 7) << 4))));
            oacc[dt] = __builtin_amdgcn_mfma_f32_16x16x32_bf16(pf, vf, oacc[dt], 0, 0, 0);
          }
        }
      }
      __builtin_amdgcn_s_setprio(0);

      __syncthreads();  // protect Ks/Vts before next chunk's LDS writes
    }

    // output for this qtile
#pragma unroll
    for (int dt = 0; dt < 8; dt++)
#pragma unroll
      for (int reg = 0; reg < 4; reg++) {
        float o = oacc[dt][reg] / l_run[reg];
        int row = qb + wave * 16 + quad * 4 + reg;
        int col = h * 128 + dt * 16 + l16;
        Ob[(size_t)row * 4096 + col] = f2bf(o);
      }
  }
}

extern "C" void kernel_launch(void* const* d_in, const int* in_sizes, int n_in,
                              void* d_out, int out_size, void* d_ws, size_t ws_size,
                              hipStream_t stream) {
  const float* x     = (const float*)d_in[0];
  const float* cosf  = (const float*)d_in[1];
  const float* sinf  = (const float*)d_in[2];
  const int*   pos   = (const int*)d_in[3];
  const float* ck_in = (const float*)d_in[5];
  const float* cv_in = (const float*)d_in[6];
  const float* Wqkv  = (const float*)d_in[7];
  const float* Wo    = (const float*)d_in[8];

  float* out    = (float*)d_out;
  float* ck_out = out + (size_t)2048 * 4096;
  float* cv_out = ck_out + (size_t)4096 * 8 * 128;

  char* ws = (char*)d_ws;

  if (ws_size >= 104857600ull) {
    uint16_t* xqkv_bf = (uint16_t*)(ws);
    uint16_t* attn_bf = (uint16_t*)(ws);
    uint16_t* x_bf    = (uint16_t*)(ws + 25165824);
    uint16_t* q_bf    = (uint16_t*)(ws + 25165824);
    uint16_t* k_bf    = (uint16_t*)(ws + 41943040);
    uint16_t* v_bf    = (uint16_t*)(ws + 46137344);
    uint16_t* vt_bf   = (uint16_t*)(ws + 50331648);
    uint16_t* wq_bf   = (uint16_t*)(ws + 54525952);
    uint16_t* wo_bf   = (uint16_t*)(ws + 54525952);

    cast_kernel<<<4096, 256, 0, stream>>>(x, x_bf, 1048576);
    cast_kernel<<<12288, 256, 0, stream>>>(Wqkv, wq_bf, 3145728);

    gemm_nt_bf16<1><<<dim3(48, 16), 256, 0, stream>>>(x_bf, wq_bf, xqkv_bf, 2048, 6144, 4096);

    copy2_kernel<<<4096, 256, 0, stream>>>(ck_in, ck_out, cv_in, cv_out, 1048576);

    rope_kernel<<<dim3(2048, 3), 256, 0, stream>>>(xqkv_bf, cosf, sinf, pos,
                                                   q_bf, k_bf, v_bf, ck_out, cv_out);

    vtrans_kernel<<<dim3(32, 4, 8), 256, 0, stream>>>(v_bf, vt_bf);

    flash_kernel<<<dim3(16, 32), 256, 0, stream>>>(q_bf, k_bf, vt_bf, attn_bf);

    cast_kernel<<<8192, 256, 0, stream>>>(Wo, wo_bf, 2097152);

    gemm_nt_bf16<0><<<dim3(32, 16), 256, 0, stream>>>(attn_bf, wo_bf, out, 2048, 4096, 4096);
  } else {
    uint16_t* xqkv_bf = (uint16_t*)(ws);
    uint16_t* attn_bf = (uint16_t*)(ws);
    uint16_t* q_bf    = (uint16_t*)(ws + 25165824);
    uint16_t* k_bf    = (uint16_t*)(ws + 41943040);
    uint16_t* v_bf    = (uint16_t*)(ws + 46137344);
    uint16_t* vt_bf   = (uint16_t*)(ws + 50331648);

    gemm_bt<0, 1><<<dim3(48, 16), 256, 0, stream>>>(x, Wqkv, xqkv_bf, 2048, 6144, 4096);
    copy2_kernel<<<4096, 256, 0, stream>>>(ck_in, ck_out, cv_in, cv_out, 1048576);
    rope_kernel<<<dim3(2048, 3), 256, 0, stream>>>(xqkv_bf, cosf, sinf, pos,
                                                   q_bf, k_bf, v_bf, ck_out, cv_out);
    vtrans_kernel<<<dim3(32, 4, 8), 256, 0, stream>>>(v_bf, vt_bf);
    flash_kernel<<<dim3(16, 32), 256, 0, stream>>>(q_bf, k_bf, vt_bf, attn_bf);
    gemm_bt<1, 0><<<dim3(32, 16), 256, 0, stream>>>(attn_bf, Wo, out, 2048, 4096, 4096);
  }
}

// Round 4
// 606.146 us; speedup vs baseline: 1.1588x; 1.0140x over previous
//
#include <hip/hip_runtime.h>
#include <stdint.h>

typedef __bf16   bf16x8 __attribute__((ext_vector_type(8)));
typedef float    f32x4  __attribute__((ext_vector_type(4)));
typedef uint16_t u16x8  __attribute__((ext_vector_type(8)));

__device__ __forceinline__ uint16_t f2bf(float f) {
  uint32_t b = __builtin_bit_cast(uint32_t, f);
  b += 0x7fffu + ((b >> 16) & 1u);
  return (uint16_t)(b >> 16);
}
__device__ __forceinline__ float bf2f(uint16_t u) {
  return __builtin_bit_cast(float, ((uint32_t)u) << 16);
}
__device__ __forceinline__ u16x8 ldcvt8(const float* __restrict__ p) {
  f32x4 lo = *(const f32x4*)p;
  f32x4 hi = *(const f32x4*)(p + 4);
  u16x8 o;
  o[0] = f2bf(lo[0]); o[1] = f2bf(lo[1]); o[2] = f2bf(lo[2]); o[3] = f2bf(lo[3]);
  o[4] = f2bf(hi[0]); o[5] = f2bf(hi[1]); o[6] = f2bf(hi[2]); o[7] = f2bf(hi[3]);
  return o;
}

typedef const __attribute__((address_space(1))) uint32_t cga_u32;
typedef __attribute__((address_space(3))) uint32_t lds_u32;
__device__ __forceinline__ void gload16(const uint16_t* g, uint16_t* l) {
  __builtin_amdgcn_global_load_lds((cga_u32*)g, (lds_u32*)l, 16, 0, 0);
}

// ---------------- fp32 -> bf16 cast ----------------
__global__ __launch_bounds__(256) void cast_kernel(const float* __restrict__ in,
                                                   uint16_t* __restrict__ out, int n8) {
  int i = blockIdx.x * 256 + threadIdx.x;
  if (i >= n8) return;
  u16x8 o = ldcvt8(in + (size_t)i * 8);
  *(u16x8*)(out + (size_t)i * 8) = o;
}

// ---------------- copy both caches ----------------
__global__ __launch_bounds__(256) void copy2_kernel(const float* __restrict__ a, float* __restrict__ da,
                                                    const float* __restrict__ b, float* __restrict__ db,
                                                    int n4) {
  int i = blockIdx.x * 256 + threadIdx.x;
  if (i >= n4) return;
  *(f32x4*)(da + (size_t)i * 4) = *(const f32x4*)(a + (size_t)i * 4);
  *(f32x4*)(db + (size_t)i * 4) = *(const f32x4*)(b + (size_t)i * 4);
}

// ---------------- 256x256 8-wave 4-phase NT GEMM (T2+T3+T4+T5) ----------------
// C[M][N] = sum_k A[m][k]*B[n][k], A,B bf16 K-major. BK=64, 512 thr (2Mx4N waves),
// per-wave out 128x64 (acc[8][4]). LDS: A triple-buffer (staged t+2), B double
// (staged t+1) = 160KB. Per K-tile: 4 phases (C quadrants), each {ds_read subtile,
// 2x gload_lds, s_barrier, lgkmcnt(0), 16 MFMA (setprio), s_barrier}; one counted
// vmcnt(4) per tile (retires exactly tile t+1's 8 loads; never drains prefetch).
// Swizzle: LDS row stride 128B; content(row,cb)=global(row, cb ^ ((row&7)<<4)),
// applied via pre-swizzled global source (linear gload_lds dest) + swizzled ds_read.
template <int OUT_BF16>
__global__ __launch_bounds__(512, 2) void gemm256(const uint16_t* __restrict__ A,
                                                  const uint16_t* __restrict__ B,
                                                  void* __restrict__ Cout,
                                                  int M, int N, int K) {
  __shared__ __align__(16) uint16_t AS[3][256 * 64];
  __shared__ __align__(16) uint16_t BS[2][256 * 64];
  const int tid = threadIdx.x;
  const int lane = tid & 63, wave = tid >> 6;
  const int l16 = lane & 15, quad = lane >> 4;
  const int wm = wave >> 2;   // 0..1  M half
  const int wn = wave & 3;    // 0..3  N quarter
  const int bm = blockIdx.y, bn = blockIdx.x;
  const int NT = K >> 6;

  f32x4 acc[8][4] = {};

  // staging map (per-thread constants): issue covers 64 rows x 128B; thread t ->
  // row sr = tid>>3, dest col (tid&7)*16B; source col pre-swizzled by row&7.
  const int sr = tid >> 3;
  const int sc = ((tid & 7) ^ (sr & 7)) << 3;  // u16
  const uint16_t* Asrc = A + (size_t)(bm * 256 + sr) * K + sc;
  const uint16_t* Bsrc = B + (size_t)(bn * 256 + sr) * K + sc;
  const size_t rs64 = (size_t)64 * K;

  // swizzled ds_read byte offsets (row*128 + ((ks*64 | quad*16) ^ ((row&7)<<4)))
  int aoff[8][2], boff[4][2];
#pragma unroll
  for (int mr = 0; mr < 8; mr++)
#pragma unroll
    for (int ks = 0; ks < 2; ks++)
      aoff[mr][ks] = (wm * 128 + mr * 16 + l16) * 128 +
                     (((ks << 6) | (quad << 4)) ^ ((l16 & 7) << 4));
#pragma unroll
  for (int nr = 0; nr < 4; nr++)
#pragma unroll
    for (int ks = 0; ks < 2; ks++)
      boff[nr][ks] = (wn * 64 + nr * 16 + l16) * 128 +
                     (((ks << 6) | (quad << 4)) ^ ((l16 & 7) << 4));

  auto stageA = [&](int buf, int h, int t) {  // half h of A K-tile t -> AS[buf]
    const uint16_t* s = Asrc + (size_t)(h * 128) * K + (size_t)t * 64;
    uint16_t* d = &AS[buf][h * 8192 + tid * 8];
    gload16(s, d);
    gload16(s + rs64, d + 4096);
  };
  auto stageB = [&](int buf, int h, int t) {
    const uint16_t* s = Bsrc + (size_t)(h * 128) * K + (size_t)t * 64;
    uint16_t* d = &BS[buf][h * 8192 + tid * 8];
    gload16(s, d);
    gload16(s + rs64, d + 4096);
  };

  // prologue: tile0 A+B (8 loads), tile1 A halves (4 loads); wait tile0 only.
  stageA(0, 0, 0); stageA(0, 1, 0); stageB(0, 0, 0); stageB(0, 1, 0);
  stageA(1, 0, 1); stageA(1, 1, 1);
  asm volatile("s_waitcnt vmcnt(4)" ::: "memory");
  __builtin_amdgcn_s_barrier();

  int ca = 0;  // A read buffer (mod 3)
  for (int t = 0; t < NT; t++) {
    const int cb = t & 1, nb = cb ^ 1;
    const int na3 = (ca + 2 >= 3) ? ca - 1 : ca + 2;  // (ca+2)%3
    const char* Ab = (const char*)AS[ca];
    const char* Bb = (const char*)BS[cb];
    bf16x8 aF[4][2], bF[4][2];

    // ---- phase 0: quadrant (mh0, nh0) ----
#pragma unroll
    for (int m4 = 0; m4 < 4; m4++)
#pragma unroll
      for (int ks = 0; ks < 2; ks++)
        aF[m4][ks] = __builtin_bit_cast(bf16x8, *(const u16x8*)(Ab + aoff[m4][ks]));
#pragma unroll
    for (int n2 = 0; n2 < 2; n2++)
#pragma unroll
      for (int ks = 0; ks < 2; ks++)
        bF[n2][ks] = __builtin_bit_cast(bf16x8, *(const u16x8*)(Bb + boff[n2][ks]));
    if (t + 1 < NT) stageB(nb, 0, t + 1);
    __builtin_amdgcn_s_barrier();
    asm volatile("s_waitcnt lgkmcnt(0)" ::: "memory");
    __builtin_amdgcn_sched_barrier(0);
    __builtin_amdgcn_s_setprio(1);
#pragma unroll
    for (int m4 = 0; m4 < 4; m4++)
#pragma unroll
      for (int n2 = 0; n2 < 2; n2++)
#pragma unroll
        for (int ks = 0; ks < 2; ks++)
          acc[m4][n2] = __builtin_amdgcn_mfma_f32_16x16x32_bf16(aF[m4][ks], bF[n2][ks], acc[m4][n2], 0, 0, 0);
    __builtin_amdgcn_s_setprio(0);
    __builtin_amdgcn_s_barrier();

    // ---- phase 1: quadrant (mh0, nh1) ----
#pragma unroll
    for (int n2 = 0; n2 < 2; n2++)
#pragma unroll
      for (int ks = 0; ks < 2; ks++)
        bF[2 + n2][ks] = __builtin_bit_cast(bf16x8, *(const u16x8*)(Bb + boff[2 + n2][ks]));
    if (t + 1 < NT) stageB(nb, 1, t + 1);
    __builtin_amdgcn_s_barrier();
    asm volatile("s_waitcnt lgkmcnt(0)" ::: "memory");
    __builtin_amdgcn_sched_barrier(0);
    __builtin_amdgcn_s_setprio(1);
#pragma unroll
    for (int m4 = 0; m4 < 4; m4++)
#pragma unroll
      for (int n2 = 0; n2 < 2; n2++)
#pragma unroll
        for (int ks = 0; ks < 2; ks++)
          acc[m4][2 + n2] = __builtin_amdgcn_mfma_f32_16x16x32_bf16(aF[m4][ks], bF[2 + n2][ks], acc[m4][2 + n2], 0, 0, 0);
    __builtin_amdgcn_s_setprio(0);
    __builtin_amdgcn_s_barrier();

    // ---- phase 2: quadrant (mh1, nh0) ----
#pragma unroll
    for (int m4 = 0; m4 < 4; m4++)
#pragma unroll
      for (int ks = 0; ks < 2; ks++)
        aF[m4][ks] = __builtin_bit_cast(bf16x8, *(const u16x8*)(Ab + aoff[4 + m4][ks]));
    if (t + 2 < NT) stageA(na3, 0, t + 2);
    __builtin_amdgcn_s_barrier();
    asm volatile("s_waitcnt lgkmcnt(0)" ::: "memory");
    __builtin_amdgcn_sched_barrier(0);
    __builtin_amdgcn_s_setprio(1);
#pragma unroll
    for (int m4 = 0; m4 < 4; m4++)
#pragma unroll
      for (int n2 = 0; n2 < 2; n2++)
#pragma unroll
        for (int ks = 0; ks < 2; ks++)
          acc[4 + m4][n2] = __builtin_amdgcn_mfma_f32_16x16x32_bf16(aF[m4][ks], bF[n2][ks], acc[4 + m4][n2], 0, 0, 0);
    __builtin_amdgcn_s_setprio(0);
    __builtin_amdgcn_s_barrier();

    // ---- phase 3: quadrant (mh1, nh1), no new ds_reads ----
    if (t + 2 < NT) stageA(na3, 1, t + 2);
    if (t < NT - 2) asm volatile("s_waitcnt vmcnt(4)" ::: "memory");
    else            asm volatile("s_waitcnt vmcnt(0)" ::: "memory");
    __builtin_amdgcn_s_barrier();
    __builtin_amdgcn_s_setprio(1);
#pragma unroll
    for (int m4 = 0; m4 < 4; m4++)
#pragma unroll
      for (int n2 = 0; n2 < 2; n2++)
#pragma unroll
        for (int ks = 0; ks < 2; ks++)
          acc[4 + m4][2 + n2] = __builtin_amdgcn_mfma_f32_16x16x32_bf16(aF[m4][ks], bF[2 + n2][ks], acc[4 + m4][2 + n2], 0, 0, 0);
    __builtin_amdgcn_s_setprio(0);
    __builtin_amdgcn_s_barrier();

    ca = (ca == 2) ? 0 : ca + 1;
  }

  // C/D layout: row = quad*4 + reg, col = l16 (m89-verified)
  const int row0 = bm * 256 + wm * 128 + quad * 4;
  const int col0 = bn * 256 + wn * 64 + l16;
#pragma unroll
  for (int mr = 0; mr < 8; mr++)
#pragma unroll
    for (int nr = 0; nr < 4; nr++)
#pragma unroll
      for (int r = 0; r < 4; r++) {
        size_t idx = (size_t)(row0 + mr * 16 + r) * N + (col0 + nr * 16);
        if constexpr (OUT_BF16) ((uint16_t*)Cout)[idx] = f2bf(acc[mr][nr][r]);
        else                    ((float*)Cout)[idx]    = acc[mr][nr][r];
      }
}

// ---------------- bf16 NT GEMM, m97 structure (fallback) ----------------
template <int OUT_BF16>
__global__ __launch_bounds__(256) void gemm_nt_bf16(const uint16_t* __restrict__ A,
                                                    const uint16_t* __restrict__ B,
                                                    void* __restrict__ Cout,
                                                    int M, int N, int K) {
  __shared__ __align__(16) uint16_t As[128 * 32];
  __shared__ __align__(16) uint16_t Bs[128 * 32];
  const int tid = threadIdx.x;
  const int lane = tid & 63, wave = tid >> 6;
  const int l16 = lane & 15, quad = lane >> 4;
  const int wm = (wave & 1) << 6, wn = (wave >> 1) << 6;
  const int bm = blockIdx.y, bn = blockIdx.x;

  f32x4 acc[4][4] = {};

  const int srow = wave * 16 + (lane >> 2);
  const int schunk = lane & 3;
  const uint16_t* Ag = A + (size_t)(bm * 128 + srow) * K + schunk * 8;
  const uint16_t* Bg = B + (size_t)(bn * 128 + srow) * K + schunk * 8;
  const size_t rs64 = (size_t)64 * K;
  uint16_t* AsD0 = &As[srow * 32 + schunk * 8];
  uint16_t* AsD1 = AsD0 + 64 * 32;
  uint16_t* BsD0 = &Bs[srow * 32 + schunk * 8];
  uint16_t* BsD1 = BsD0 + 64 * 32;

  for (int k0 = 0; k0 < K; k0 += 32) {
    gload16(Ag, AsD0);
    gload16(Ag + rs64, AsD1);
    gload16(Bg, BsD0);
    gload16(Bg + rs64, BsD1);
    Ag += 32; Bg += 32;
    __syncthreads();
    bf16x8 af[4], bfr[4];
#pragma unroll
    for (int i = 0; i < 4; i++) {
      af[i]  = __builtin_bit_cast(bf16x8, *(const u16x8*)&As[(wm + i * 16 + l16) * 32 + quad * 8]);
      bfr[i] = __builtin_bit_cast(bf16x8, *(const u16x8*)&Bs[(wn + i * 16 + l16) * 32 + quad * 8]);
    }
#pragma unroll
    for (int i = 0; i < 4; i++)
#pragma unroll
      for (int j = 0; j < 4; j++)
        acc[i][j] = __builtin_amdgcn_mfma_f32_16x16x32_bf16(af[i], bfr[j], acc[i][j], 0, 0, 0);
    __syncthreads();
  }

  const int row0 = bm * 128 + wm + quad * 4;
  const int col0 = bn * 128 + wn + l16;
#pragma unroll
  for (int i = 0; i < 4; i++)
#pragma unroll
    for (int j = 0; j < 4; j++)
#pragma unroll
      for (int r = 0; r < 4; r++) {
        size_t idx = (size_t)(row0 + i * 16 + r) * N + (col0 + j * 16);
        if constexpr (OUT_BF16) ((uint16_t*)Cout)[idx] = f2bf(acc[i][j][r]);
        else                    ((float*)Cout)[idx]    = acc[i][j][r];
      }
}

// ---------------- fallback NT GEMM (fused fp32 cast, reg-staged) ----------------
template <int A_BF16, int OUT_BF16>
__global__ __launch_bounds__(256) void gemm_bt(const void* __restrict__ Ap,
                                               const float* __restrict__ B,
                                               void* __restrict__ Cout, int M, int N, int K) {
  constexpr int PAD = 40;
  __shared__ __align__(16) uint16_t As[128 * PAD];
  __shared__ __align__(16) uint16_t Bs[128 * PAD];
  const int tid = threadIdx.x;
  const int lane = tid & 63, wave = tid >> 6;
  const int l16 = lane & 15, quad = lane >> 4;
  const int wm = (wave & 1) << 6, wn = (wave >> 1) << 6;
  const int bm = blockIdx.y, bn = blockIdx.x;

  f32x4 acc[4][4] = {};

  const int srow = tid >> 2;
  const int scol = (tid & 3) << 3;
  const size_t aoff = (size_t)(bm * 128 + srow) * K + scol;
  const uint16_t* Agh = (const uint16_t*)Ap + aoff;
  const float*    Agf = (const float*)Ap + aoff;
  const float*    Bg  = B + (size_t)(bn * 128 + srow) * K + scol;
  const size_t rstride = (size_t)64 * K;

  for (int k0 = 0; k0 < K; k0 += 32) {
    u16x8 a0, a1;
    if constexpr (A_BF16) {
      a0 = *(const u16x8*)Agh;
      a1 = *(const u16x8*)(Agh + rstride);
      Agh += 32;
    } else {
      a0 = ldcvt8(Agf);
      a1 = ldcvt8(Agf + rstride);
      Agf += 32;
    }
    u16x8 b0 = ldcvt8(Bg);
    u16x8 b1 = ldcvt8(Bg + rstride);
    Bg += 32;
    __syncthreads();
    *(u16x8*)&As[srow * PAD + scol] = a0;
    *(u16x8*)&As[(srow + 64) * PAD + scol] = a1;
    *(u16x8*)&Bs[srow * PAD + scol] = b0;
    *(u16x8*)&Bs[(srow + 64) * PAD + scol] = b1;
    __syncthreads();
    bf16x8 af[4], bfr[4];
#pragma unroll
    for (int i = 0; i < 4; i++) {
      af[i]  = __builtin_bit_cast(bf16x8, *(const u16x8*)&As[(wm + i * 16 + l16) * PAD + quad * 8]);
      bfr[i] = __builtin_bit_cast(bf16x8, *(const u16x8*)&Bs[(wn + i * 16 + l16) * PAD + quad * 8]);
    }
#pragma unroll
    for (int i = 0; i < 4; i++)
#pragma unroll
      for (int j = 0; j < 4; j++)
        acc[i][j] = __builtin_amdgcn_mfma_f32_16x16x32_bf16(af[i], bfr[j], acc[i][j], 0, 0, 0);
  }

  const int row0 = bm * 128 + wm + quad * 4;
  const int col0 = bn * 128 + wn + l16;
#pragma unroll
  for (int i = 0; i < 4; i++)
#pragma unroll
    for (int j = 0; j < 4; j++)
#pragma unroll
      for (int r = 0; r < 4; r++) {
        size_t idx = (size_t)(row0 + i * 16 + r) * N + (col0 + j * 16);
        if constexpr (OUT_BF16) ((uint16_t*)Cout)[idx] = f2bf(acc[i][j][r]);
        else                    ((float*)Cout)[idx]    = acc[i][j][r];
      }
}

// ---------------- RoPE + cache scatter + attention-buffer emit ----------------
__global__ __launch_bounds__(256) void rope_kernel(const uint16_t* __restrict__ xqkv,
    const float* __restrict__ cosf, const float* __restrict__ sinf,
    const int* __restrict__ pos,
    uint16_t* __restrict__ qb, uint16_t* __restrict__ kb, uint16_t* __restrict__ vb,
    float* __restrict__ ck, float* __restrict__ cv) {
  const float QS = 0.12751743f;  // 128^-0.5 * log2(e)
  const int s = blockIdx.x;
  const int e0 = (blockIdx.y * 256 + threadIdx.x) * 8;
  const int head = e0 >> 7;
  const int d0 = e0 & 127;
  u16x8 u = *(const u16x8*)(xqkv + (size_t)s * 6144 + e0);
  float x[8];
#pragma unroll
  for (int j = 0; j < 8; j++) x[j] = bf2f(u[j]);

  if (head < 40) {
    const int i0 = d0 >> 1;
    f32x4 c4 = *(const f32x4*)(cosf + (size_t)s * 64 + i0);
    f32x4 s4 = *(const f32x4*)(sinf + (size_t)s * 64 + i0);
    float o[8];
#pragma unroll
    for (int kk = 0; kk < 4; kk++) {
      float x1 = x[2 * kk], x2 = x[2 * kk + 1];
      o[2 * kk]     = x1 * c4[kk] - x2 * s4[kk];
      o[2 * kk + 1] = x1 * s4[kk] + x2 * c4[kk];
    }
    if (head < 32) {
      u16x8 ob;
#pragma unroll
      for (int j = 0; j < 8; j++) ob[j] = f2bf(o[j] * QS);
      *(u16x8*)(qb + (size_t)s * 4096 + head * 128 + d0) = ob;
    } else {
      u16x8 ob;
#pragma unroll
      for (int j = 0; j < 8; j++) ob[j] = f2bf(o[j]);
      int kvh = head - 32;
      *(u16x8*)(kb + ((size_t)kvh * 2048 + s) * 128 + d0) = ob;
      int p = pos[s];
      if ((unsigned)p < 4096u) {
        float* dst = ck + ((size_t)p * 8 + kvh) * 128 + d0;
#pragma unroll
        for (int j = 0; j < 8; j++) dst[j] = o[j];
      }
    }
  } else {
    int kvh = head - 40;
    *(u16x8*)(vb + ((size_t)kvh * 2048 + s) * 128 + d0) = u;
    int p = pos[s];
    if ((unsigned)p < 4096u) {
      float* dst = cv + ((size_t)p * 8 + kvh) * 128 + d0;
#pragma unroll
      for (int j = 0; j < 8; j++) dst[j] = x[j];
    }
  }
}

// ---------------- V transpose per kv head ----------------
__global__ __launch_bounds__(256) void vtrans_kernel(const uint16_t* __restrict__ vb,
                                                     uint16_t* __restrict__ vt) {
  __shared__ __align__(16) uint16_t t[32 * 72];
  const int h = blockIdx.z;
  const int s0 = blockIdx.x * 64, d0 = blockIdx.y * 32;
  const uint16_t* in = vb + (size_t)h * 2048 * 128;
  uint16_t* out = vt + (size_t)h * 128 * 2048;
  const int tid = threadIdx.x;
  {
    int r = tid >> 2, c8 = (tid & 3) * 8;
    u16x8 v = *(const u16x8*)(in + (size_t)(s0 + r) * 128 + d0 + c8);
#pragma unroll
    for (int j = 0; j < 8; j++) t[(c8 + j) * 72 + r] = v[j];
  }
  __syncthreads();
  {
    int r = tid >> 3, c8 = (tid & 7) * 8;
    u16x8 v = *(const u16x8*)&t[r * 72 + c8];
    *(u16x8*)(out + (size_t)(d0 + r) * 2048 + s0 + c8) = v;
  }
}

// ---------------- flash attention v3 (qtile-paired, base-2 softmax) ----------------
__global__ __launch_bounds__(256) void flash_kernel(const uint16_t* __restrict__ Qb,
    const uint16_t* __restrict__ Kb, const uint16_t* __restrict__ Vtb,
    uint16_t* __restrict__ Ob) {
  __shared__ __align__(16) uint16_t Ks[64 * 128];
  __shared__ __align__(16) uint16_t Vts[128 * 64];
  __shared__ __align__(16) uint16_t Ps[4][16 * 64];
  const int tid = threadIdx.x;
  const int lane = tid & 63, wave = tid >> 6;
  const int l16 = lane & 15, quad = lane >> 4;
  const int h = blockIdx.y, kvh = h >> 2;
  const uint16_t* Kg = Kb + (size_t)kvh * 2048 * 128;
  const uint16_t* Vg = Vtb + (size_t)kvh * 128 * 2048;

  u16x8 kreg[4], vreg[4];
  const int krr = tid >> 4, kcb = (tid & 15) * 16;
  const int vrr = tid >> 3, vcb = (tid & 7) * 16;

  for (int ph = 0; ph < 2; ph++) {
    const int qtile = ph ? (int)blockIdx.x : 31 - (int)blockIdx.x;
    const int qb = qtile * 64;
    const int nch = qtile + 1;
    const int qmax = qb + wave * 16 + 15;

    bf16x8 qf[4];
    {
      const uint16_t* Qg = Qb + (size_t)(qb + wave * 16 + l16) * 4096 + h * 128 + quad * 8;
#pragma unroll
      for (int dc = 0; dc < 4; dc++)
        qf[dc] = __builtin_bit_cast(bf16x8, *(const u16x8*)(Qg + dc * 32));
    }

    f32x4 oacc[8] = {};
    float m_run[4], l_run[4];
#pragma unroll
    for (int r = 0; r < 4; r++) { m_run[r] = -1e30f; l_run[r] = 0.f; }

#pragma unroll
    for (int i = 0; i < 4; i++)
      kreg[i] = *(const u16x8*)(Kg + (size_t)(krr + i * 16) * 128 + kcb / 2);
#pragma unroll
    for (int i = 0; i < 4; i++)
      vreg[i] = *(const u16x8*)(Vg + (size_t)(vrr + i * 32) * 2048 + vcb / 2);

    for (int ch = 0; ch < nch; ch++) {
      const int cb = ch * 64;
#pragma unroll
      for (int i = 0; i < 4; i++) {
        int r = krr + i * 16;
        *(u16x8*)((char*)Ks + r * 256 + (kcb ^ ((r & 7) << 4))) = kreg[i];
      }
#pragma unroll
      for (int i = 0; i < 4; i++) {
        int r = vrr + i * 32;
        *(u16x8*)((char*)Vts + r * 128 + (vcb ^ ((r & 7) << 4))) = vreg[i];
      }
      __syncthreads();

      if (ch + 1 < nch) {
        const int nb = cb + 64;
#pragma unroll
        for (int i = 0; i < 4; i++)
          kreg[i] = *(const u16x8*)(Kg + (size_t)(nb + krr + i * 16) * 128 + kcb / 2);
#pragma unroll
        for (int i = 0; i < 4; i++)
          vreg[i] = *(const u16x8*)(Vg + (size_t)(vrr + i * 32) * 2048 + nb + vcb / 2);
      }

      f32x4 sacc[4] = {};
      __builtin_amdgcn_s_setprio(1);
#pragma unroll
      for (int ni = 0; ni < 4; ni++) {
        if (cb + ni * 16 <= qmax) {
#pragma unroll
          for (int dc = 0; dc < 4; dc++) {
            int r = ni * 16 + l16;
            bf16x8 kf = __builtin_bit_cast(bf16x8,
                *(const u16x8*)((const char*)Ks + r * 256 + ((dc * 64 + quad * 16) ^ ((r & 7) << 4))));
            sacc[ni] = __builtin_amdgcn_mfma_f32_16x16x32_bf16(qf[dc], kf, sacc[ni], 0, 0, 0);
          }
        }
      }
      __builtin_amdgcn_s_setprio(0);

      float p[4][4], alpha[4];
#pragma unroll
      for (int reg = 0; reg < 4; reg++) {
        const int q = qb + wave * 16 + quad * 4 + reg;
        float mx = -1e30f;
#pragma unroll
        for (int ni = 0; ni < 4; ni++) {
          float sv = sacc[ni][reg];
          if (cb + ni * 16 + l16 > q) sv = -1e30f;
          p[ni][reg] = sv;
          mx = fmaxf(mx, sv);
        }
#pragma unroll
        for (int off = 8; off >= 1; off >>= 1)
          mx = fmaxf(mx, __shfl_xor(mx, off, 64));
        float mn = fmaxf(m_run[reg], mx);
        alpha[reg] = __builtin_amdgcn_exp2f(m_run[reg] - mn);
        m_run[reg] = mn;
        float rs = 0.f;
#pragma unroll
        for (int ni = 0; ni < 4; ni++) {
          float e = __builtin_amdgcn_exp2f(p[ni][reg] - mn);
          p[ni][reg] = e;
          rs += e;
        }
#pragma unroll
        for (int off = 8; off >= 1; off >>= 1)
          rs += __shfl_xor(rs, off, 64);
        l_run[reg] = l_run[reg] * alpha[reg] + rs;
      }

#pragma unroll
      for (int dt = 0; dt < 8; dt++)
#pragma unroll
        for (int reg = 0; reg < 4; reg++)
          oacc[dt][reg] *= alpha[reg];

      uint16_t* Pw = Ps[wave];
#pragma unroll
      for (int ni = 0; ni < 4; ni++)
#pragma unroll
        for (int reg = 0; reg < 4; reg++) {
          int r = quad * 4 + reg;
          *(uint16_t*)((char*)Pw + r * 128 + ((ni * 32 + l16 * 2) ^ ((r & 7) << 4))) =
              f2bf(p[ni][reg]);
        }

      __builtin_amdgcn_s_setprio(1);
#pragma unroll
      for (int kc = 0; kc < 2; kc++) {
        if (cb + kc * 32 <= qmax) {
          bf16x8 pf = __builtin_bit_cast(bf16x8,
              *(const u16x8*)((const char*)Pw + l16 * 128 + ((kc * 64 + quad * 16) ^ ((l16 & 7) << 4))));
#pragma unroll
          for (int dt = 0; dt < 8; dt++) {
            int r = dt * 16 + l16;
            bf16x8 vf = __builtin_bit_cast(bf16x8,
                *(const u16x8*)((const char*)Vts + r * 128 + ((kc * 64 + quad * 16) ^ ((r & 7) << 4))));
            oacc[dt] = __builtin_amdgcn_mfma_f32_16x16x32_bf16(pf, vf, oacc[dt], 0, 0, 0);
          }
        }
      }
      __builtin_amdgcn_s_setprio(0);

      __syncthreads();
    }

#pragma unroll
    for (int dt = 0; dt < 8; dt++)
#pragma unroll
      for (int reg = 0; reg < 4; reg++) {
        float o = oacc[dt][reg] / l_run[reg];
        int row = qb + wave * 16 + quad * 4 + reg;
        int col = h * 128 + dt * 16 + l16;
        Ob[(size_t)row * 4096 + col] = f2bf(o);
      }
  }
}

extern "C" void kernel_launch(void* const* d_in, const int* in_sizes, int n_in,
                              void* d_out, int out_size, void* d_ws, size_t ws_size,
                              hipStream_t stream) {
  const float* x     = (const float*)d_in[0];
  const float* cosf  = (const float*)d_in[1];
  const float* sinf  = (const float*)d_in[2];
  const int*   pos   = (const int*)d_in[3];
  const float* ck_in = (const float*)d_in[5];
  const float* cv_in = (const float*)d_in[6];
  const float* Wqkv  = (const float*)d_in[7];
  const float* Wo    = (const float*)d_in[8];

  float* out    = (float*)d_out;
  float* ck_out = out + (size_t)2048 * 4096;
  float* cv_out = ck_out + (size_t)4096 * 8 * 128;

  char* ws = (char*)d_ws;

  if (ws_size >= 104857600ull) {
    uint16_t* xqkv_bf = (uint16_t*)(ws);
    uint16_t* attn_bf = (uint16_t*)(ws);
    uint16_t* x_bf    = (uint16_t*)(ws + 25165824);
    uint16_t* q_bf    = (uint16_t*)(ws + 25165824);
    uint16_t* k_bf    = (uint16_t*)(ws + 41943040);
    uint16_t* v_bf    = (uint16_t*)(ws + 46137344);
    uint16_t* vt_bf   = (uint16_t*)(ws + 50331648);
    uint16_t* wq_bf   = (uint16_t*)(ws + 54525952);
    uint16_t* wo_bf   = (uint16_t*)(ws + 54525952);

    cast_kernel<<<4096, 256, 0, stream>>>(x, x_bf, 1048576);
    cast_kernel<<<12288, 256, 0, stream>>>(Wqkv, wq_bf, 3145728);

    bool ok256 = true;
    gemm256<1><<<dim3(24, 8), 512, 0, stream>>>(x_bf, wq_bf, xqkv_bf, 2048, 6144, 4096);
    if (hipGetLastError() != hipSuccess) {
      ok256 = false;
      gemm_nt_bf16<1><<<dim3(48, 16), 256, 0, stream>>>(x_bf, wq_bf, xqkv_bf, 2048, 6144, 4096);
    }

    copy2_kernel<<<4096, 256, 0, stream>>>(ck_in, ck_out, cv_in, cv_out, 1048576);

    rope_kernel<<<dim3(2048, 3), 256, 0, stream>>>(xqkv_bf, cosf, sinf, pos,
                                                   q_bf, k_bf, v_bf, ck_out, cv_out);

    vtrans_kernel<<<dim3(32, 4, 8), 256, 0, stream>>>(v_bf, vt_bf);

    flash_kernel<<<dim3(16, 32), 256, 0, stream>>>(q_bf, k_bf, vt_bf, attn_bf);

    cast_kernel<<<8192, 256, 0, stream>>>(Wo, wo_bf, 2097152);

    if (ok256) {
      gemm256<0><<<dim3(16, 8), 512, 0, stream>>>(attn_bf, wo_bf, out, 2048, 4096, 4096);
      if (hipGetLastError() != hipSuccess)
        gemm_nt_bf16<0><<<dim3(32, 16), 256, 0, stream>>>(attn_bf, wo_bf, out, 2048, 4096, 4096);
    } else {
      gemm_nt_bf16<0><<<dim3(32, 16), 256, 0, stream>>>(attn_bf, wo_bf, out, 2048, 4096, 4096);
    }
  } else {
    uint16_t* xqkv_bf = (uint16_t*)(ws);
    uint16_t* attn_bf = (uint16_t*)(ws);
    uint16_t* q_bf    = (uint16_t*)(ws + 25165824);
    uint16_t* k_bf    = (uint16_t*)(ws + 41943040);
    uint16_t* v_bf    = (uint16_t*)(ws + 46137344);
    uint16_t* vt_bf   = (uint16_t*)(ws + 50331648);

    gemm_bt<0, 1><<<dim3(48, 16), 256, 0, stream>>>(x, Wqkv, xqkv_bf, 2048, 6144, 4096);
    copy2_kernel<<<4096, 256, 0, stream>>>(ck_in, ck_out, cv_in, cv_out, 1048576);
    rope_kernel<<<dim3(2048, 3), 256, 0, stream>>>(xqkv_bf, cosf, sinf, pos,
                                                   q_bf, k_bf, v_bf, ck_out, cv_out);
    vtrans_kernel<<<dim3(32, 4, 8), 256, 0, stream>>>(v_bf, vt_bf);
    flash_kernel<<<dim3(16, 32), 256, 0, stream>>>(q_bf, k_bf, vt_bf, attn_bf);
    gemm_bt<1, 0><<<dim3(32, 16), 256, 0, stream>>>(attn_bf, Wo, out, 2048, 4096, 4096);
  }
}

// Round 5
// 591.602 us; speedup vs baseline: 1.1873x; 1.0246x over previous
//
#include <hip/hip_runtime.h>
#include <stdint.h>

typedef __bf16   bf16x8 __attribute__((ext_vector_type(8)));
typedef float    f32x4  __attribute__((ext_vector_type(4)));
typedef uint16_t u16x8  __attribute__((ext_vector_type(8)));

__device__ __forceinline__ uint16_t f2bf(float f) {
  uint32_t b = __builtin_bit_cast(uint32_t, f);
  b += 0x7fffu + ((b >> 16) & 1u);
  return (uint16_t)(b >> 16);
}
__device__ __forceinline__ float bf2f(uint16_t u) {
  return __builtin_bit_cast(float, ((uint32_t)u) << 16);
}
__device__ __forceinline__ u16x8 ldcvt8(const float* __restrict__ p) {
  f32x4 lo = *(const f32x4*)p;
  f32x4 hi = *(const f32x4*)(p + 4);
  u16x8 o;
  o[0] = f2bf(lo[0]); o[1] = f2bf(lo[1]); o[2] = f2bf(lo[2]); o[3] = f2bf(lo[3]);
  o[4] = f2bf(hi[0]); o[5] = f2bf(hi[1]); o[6] = f2bf(hi[2]); o[7] = f2bf(hi[3]);
  return o;
}

typedef const __attribute__((address_space(1))) uint32_t cga_u32;
typedef __attribute__((address_space(3))) uint32_t lds_u32;
__device__ __forceinline__ void gload16(const uint16_t* g, uint16_t* l) {
  __builtin_amdgcn_global_load_lds((cga_u32*)g, (lds_u32*)l, 16, 0, 0);
}

#define CBAR() do { asm volatile("" ::: "memory"); __builtin_amdgcn_s_barrier(); asm volatile("" ::: "memory"); } while (0)

// ---------------- fp32 -> bf16 cast ----------------
__global__ __launch_bounds__(256) void cast_kernel(const float* __restrict__ in,
                                                   uint16_t* __restrict__ out, int n8) {
  int i = blockIdx.x * 256 + threadIdx.x;
  if (i >= n8) return;
  u16x8 o = ldcvt8(in + (size_t)i * 8);
  *(u16x8*)(out + (size_t)i * 8) = o;
}

// ---------------- copy both caches ----------------
__global__ __launch_bounds__(256) void copy2_kernel(const float* __restrict__ a, float* __restrict__ da,
                                                    const float* __restrict__ b, float* __restrict__ db,
                                                    int n4) {
  int i = blockIdx.x * 256 + threadIdx.x;
  if (i >= n4) return;
  *(f32x4*)(da + (size_t)i * 4) = *(const f32x4*)(a + (size_t)i * 4);
  *(f32x4*)(db + (size_t)i * 4) = *(const f32x4*)(b + (size_t)i * 4);
}

// ---------------- split-K fixup: out = p0 + p1 ----------------
__global__ __launch_bounds__(256) void add2_kernel(const float* __restrict__ a,
                                                   const float* __restrict__ b,
                                                   float* __restrict__ o, int n4) {
  int i = blockIdx.x * 256 + threadIdx.x;
  if (i >= n4) return;
  f32x4 x = *(const f32x4*)(a + (size_t)i * 4);
  f32x4 y = *(const f32x4*)(b + (size_t)i * 4);
  x[0] += y[0]; x[1] += y[1]; x[2] += y[2]; x[3] += y[3];
  *(f32x4*)(o + (size_t)i * 4) = x;
}

// ---------------- 256x256 8-wave deep-pipeline NT GEMM (T2+T3+T4+T5) ----------------
// C[M][N] = sum_k A[m][k]*B[n][k], bf16 K-major. BK=64, 512 thr (2M x 4N waves),
// per-wave out 128x64 (acc[8][4]). LDS 128KB: AS/BS[half][parity] 16KB each.
// All ds_reads for tile t issue in phases 0-1 (front-loaded fragments) -> both
// parity-p buffers free from phase 2 -> stage tile t+2 at phases 2-3 (depth-2).
// Single vmcnt(8) per tile retires tile t+1's loads (issued 4-6 phases earlier,
// during tile t-1) while keeping t+2's 8 loads in flight. Never drains to 0 mid-loop.
// Swizzle (r4-verified, 0 conflicts): LDS[r][cb] = global[r][cb ^ ((r&7)<<4B)],
// via pre-swizzled global source (linear gload_lds dest) + swizzled ds_read.
// Split-K: blockIdx.z selects K-slice [z*Klen, (z+1)*Klen); fp32 partial per z.
template <int OUT_BF16>
__global__ __launch_bounds__(512, 2) void gemm256(const uint16_t* __restrict__ A,
                                                  const uint16_t* __restrict__ B,
                                                  void* __restrict__ Cout,
                                                  int M, int N, int K, int Klen) {
  __shared__ __align__(16) uint16_t AS[2][2][128 * 64];  // [half][parity]
  __shared__ __align__(16) uint16_t BS[2][2][128 * 64];
  const int tid = threadIdx.x;
  const int lane = tid & 63, wave = tid >> 6;
  const int l16 = lane & 15, quad = lane >> 4;
  const int wm = wave >> 2;   // 0..1  M half
  const int wn = wave & 3;    // 0..3  N quarter
  const int bm = blockIdx.y, bn = blockIdx.x;
  const int Kbase = (int)blockIdx.z * Klen;
  const int NT = Klen >> 6;

  f32x4 acc[8][4] = {};

  // staging: thread covers rows (tid>>3) and (tid>>3)+64 of a 128-row half, 16B each.
  // dest is lane-linear (lane l -> base + 16*l); source col pre-swizzled by row&7.
  const int sr = tid >> 3;
  const int sc = ((tid & 7) ^ (sr & 7)) << 3;  // u16 units
  const uint16_t* Asrc = A + (size_t)(bm * 256 + sr) * K + Kbase + sc;
  const uint16_t* Bsrc = B + (size_t)(bn * 256 + sr) * K + Kbase + sc;
  const size_t rs64 = (size_t)64 * K;
  const int dstoff = (tid >> 3) * 64 + (tid & 7) * 8;

  // swizzled ds_read byte offsets
  int aoffB[8][2], boffB[4][2];
#pragma unroll
  for (int mr = 0; mr < 8; mr++)
#pragma unroll
    for (int ks = 0; ks < 2; ks++) {
      int la = mr * 16 + l16;
      aoffB[mr][ks] = la * 128 + (((ks << 6) | (quad << 4)) ^ ((la & 7) << 4));
    }
#pragma unroll
  for (int nr = 0; nr < 4; nr++)
#pragma unroll
    for (int ks = 0; ks < 2; ks++) {
      int lb = (wn & 1) * 64 + nr * 16 + l16;
      boffB[nr][ks] = lb * 128 + (((ks << 6) | (quad << 4)) ^ ((lb & 7) << 4));
    }

  auto stageA = [&](int h, int p, int t) {
    const uint16_t* s = Asrc + (size_t)(h * 128) * K + (size_t)t * 64;
    uint16_t* d = &AS[h][p][dstoff];
    gload16(s, d);
    gload16(s + rs64, d + 4096);
  };
  auto stageB = [&](int h, int p, int t) {
    const uint16_t* s = Bsrc + (size_t)(h * 128) * K + (size_t)t * 64;
    uint16_t* d = &BS[h][p][dstoff];
    gload16(s, d);
    gload16(s + rs64, d + 4096);
  };

  // prologue: stage tile0 (parity0) + tile1 (parity1); wait tile0 only (8 in flight).
  stageA(0, 0, 0); stageA(1, 0, 0); stageB(0, 0, 0); stageB(1, 0, 0);
  if (1 < NT) { stageA(0, 1, 1); stageA(1, 1, 1); stageB(0, 1, 1); stageB(1, 1, 1);
                asm volatile("s_waitcnt vmcnt(8)" ::: "memory"); }
  else        { asm volatile("s_waitcnt vmcnt(0)" ::: "memory"); }
  CBAR();

  for (int t = 0; t < NT; t++) {
    const int p = t & 1;
    const char* Ab = (const char*)AS[wm][p];
    const char* Bb = (const char*)BS[wn >> 1][p];
    bf16x8 aF0[4][2], aF4[4][2], bF[4][2];

    // ---- phase 0: read aF0 (8) + bF ks0 (4); MFMA mr0-3 x ks0 ----
#pragma unroll
    for (int m = 0; m < 4; m++)
#pragma unroll
      for (int ks = 0; ks < 2; ks++)
        aF0[m][ks] = __builtin_bit_cast(bf16x8, *(const u16x8*)(Ab + aoffB[m][ks]));
#pragma unroll
    for (int nr = 0; nr < 4; nr++)
      bF[nr][0] = __builtin_bit_cast(bf16x8, *(const u16x8*)(Bb + boffB[nr][0]));
    CBAR();
    asm volatile("s_waitcnt lgkmcnt(0)" ::: "memory");
    __builtin_amdgcn_sched_barrier(0);
    __builtin_amdgcn_s_setprio(1);
#pragma unroll
    for (int m = 0; m < 4; m++)
#pragma unroll
      for (int nr = 0; nr < 4; nr++)
        acc[m][nr] = __builtin_amdgcn_mfma_f32_16x16x32_bf16(aF0[m][0], bF[nr][0], acc[m][nr], 0, 0, 0);
    __builtin_amdgcn_s_setprio(0);
    CBAR();

    // ---- phase 1: read aF4 (8) + bF ks1 (4); MFMA mr0-3 x ks1 ----
#pragma unroll
    for (int m = 0; m < 4; m++)
#pragma unroll
      for (int ks = 0; ks < 2; ks++)
        aF4[m][ks] = __builtin_bit_cast(bf16x8, *(const u16x8*)(Ab + aoffB[4 + m][ks]));
#pragma unroll
    for (int nr = 0; nr < 4; nr++)
      bF[nr][1] = __builtin_bit_cast(bf16x8, *(const u16x8*)(Bb + boffB[nr][1]));
    CBAR();
    asm volatile("s_waitcnt lgkmcnt(0)" ::: "memory");
    __builtin_amdgcn_sched_barrier(0);
    __builtin_amdgcn_s_setprio(1);
#pragma unroll
    for (int m = 0; m < 4; m++)
#pragma unroll
      for (int nr = 0; nr < 4; nr++)
        acc[m][nr] = __builtin_amdgcn_mfma_f32_16x16x32_bf16(aF0[m][1], bF[nr][1], acc[m][nr], 0, 0, 0);
    __builtin_amdgcn_s_setprio(0);
    CBAR();

    // ---- phase 2: no ds_reads; stage half0 of tile t+2 (parity p, freed after ph1) ----
    if (t + 2 < NT) { stageA(0, p, t + 2); stageB(0, p, t + 2); }
    CBAR();
    __builtin_amdgcn_s_setprio(1);
#pragma unroll
    for (int m = 0; m < 4; m++)
#pragma unroll
      for (int nr = 0; nr < 4; nr++)
        acc[4 + m][nr] = __builtin_amdgcn_mfma_f32_16x16x32_bf16(aF4[m][0], bF[nr][0], acc[4 + m][nr], 0, 0, 0);
    __builtin_amdgcn_s_setprio(0);
    CBAR();

    // ---- phase 3: stage half1 of tile t+2; counted vmcnt retires tile t+1's loads ----
    if (t + 2 < NT) {
      stageA(1, p, t + 2); stageB(1, p, t + 2);
      asm volatile("s_waitcnt vmcnt(8)" ::: "memory");
    } else {
      asm volatile("s_waitcnt vmcnt(0)" ::: "memory");
    }
    CBAR();
    __builtin_amdgcn_s_setprio(1);
#pragma unroll
    for (int m = 0; m < 4; m++)
#pragma unroll
      for (int nr = 0; nr < 4; nr++)
        acc[4 + m][nr] = __builtin_amdgcn_mfma_f32_16x16x32_bf16(aF4[m][1], bF[nr][1], acc[4 + m][nr], 0, 0, 0);
    __builtin_amdgcn_s_setprio(0);
    CBAR();
  }

  // C/D layout: row = quad*4 + reg, col = l16 (m89-verified)
  const int row0 = bm * 256 + wm * 128 + quad * 4;
  const int col0 = bn * 256 + wn * 64 + l16;
  if constexpr (OUT_BF16) {
    uint16_t* C = (uint16_t*)Cout;
#pragma unroll
    for (int mr = 0; mr < 8; mr++)
#pragma unroll
      for (int nr = 0; nr < 4; nr++)
#pragma unroll
        for (int r = 0; r < 4; r++)
          C[(size_t)(row0 + mr * 16 + r) * N + (col0 + nr * 16)] = f2bf(acc[mr][nr][r]);
  } else {
    float* C = (float*)Cout + (size_t)blockIdx.z * M * N;
#pragma unroll
    for (int mr = 0; mr < 8; mr++)
#pragma unroll
      for (int nr = 0; nr < 4; nr++)
#pragma unroll
        for (int r = 0; r < 4; r++)
          C[(size_t)(row0 + mr * 16 + r) * N + (col0 + nr * 16)] = acc[mr][nr][r];
  }
}

// ---------------- bf16 NT GEMM, m97 structure (launch-fail fallback) ----------------
template <int OUT_BF16>
__global__ __launch_bounds__(256) void gemm_nt_bf16(const uint16_t* __restrict__ A,
                                                    const uint16_t* __restrict__ B,
                                                    void* __restrict__ Cout,
                                                    int M, int N, int K) {
  __shared__ __align__(16) uint16_t As[128 * 32];
  __shared__ __align__(16) uint16_t Bs[128 * 32];
  const int tid = threadIdx.x;
  const int lane = tid & 63, wave = tid >> 6;
  const int l16 = lane & 15, quad = lane >> 4;
  const int wm = (wave & 1) << 6, wn = (wave >> 1) << 6;
  const int bm = blockIdx.y, bn = blockIdx.x;

  f32x4 acc[4][4] = {};

  const int srow = wave * 16 + (lane >> 2);
  const int schunk = lane & 3;
  const uint16_t* Ag = A + (size_t)(bm * 128 + srow) * K + schunk * 8;
  const uint16_t* Bg = B + (size_t)(bn * 128 + srow) * K + schunk * 8;
  const size_t rs64 = (size_t)64 * K;
  uint16_t* AsD0 = &As[srow * 32 + schunk * 8];
  uint16_t* AsD1 = AsD0 + 64 * 32;
  uint16_t* BsD0 = &Bs[srow * 32 + schunk * 8];
  uint16_t* BsD1 = BsD0 + 64 * 32;

  for (int k0 = 0; k0 < K; k0 += 32) {
    gload16(Ag, AsD0);
    gload16(Ag + rs64, AsD1);
    gload16(Bg, BsD0);
    gload16(Bg + rs64, BsD1);
    Ag += 32; Bg += 32;
    __syncthreads();
    bf16x8 af[4], bfr[4];
#pragma unroll
    for (int i = 0; i < 4; i++) {
      af[i]  = __builtin_bit_cast(bf16x8, *(const u16x8*)&As[(wm + i * 16 + l16) * 32 + quad * 8]);
      bfr[i] = __builtin_bit_cast(bf16x8, *(const u16x8*)&Bs[(wn + i * 16 + l16) * 32 + quad * 8]);
    }
#pragma unroll
    for (int i = 0; i < 4; i++)
#pragma unroll
      for (int j = 0; j < 4; j++)
        acc[i][j] = __builtin_amdgcn_mfma_f32_16x16x32_bf16(af[i], bfr[j], acc[i][j], 0, 0, 0);
    __syncthreads();
  }

  const int row0 = bm * 128 + wm + quad * 4;
  const int col0 = bn * 128 + wn + l16;
#pragma unroll
  for (int i = 0; i < 4; i++)
#pragma unroll
    for (int j = 0; j < 4; j++)
#pragma unroll
      for (int r = 0; r < 4; r++) {
        size_t idx = (size_t)(row0 + i * 16 + r) * N + (col0 + j * 16);
        if constexpr (OUT_BF16) ((uint16_t*)Cout)[idx] = f2bf(acc[i][j][r]);
        else                    ((float*)Cout)[idx]    = acc[i][j][r];
      }
}

// ---------------- fallback NT GEMM (fused fp32 cast, reg-staged) ----------------
template <int A_BF16, int OUT_BF16>
__global__ __launch_bounds__(256) void gemm_bt(const void* __restrict__ Ap,
                                               const float* __restrict__ B,
                                               void* __restrict__ Cout, int M, int N, int K) {
  constexpr int PAD = 40;
  __shared__ __align__(16) uint16_t As[128 * PAD];
  __shared__ __align__(16) uint16_t Bs[128 * PAD];
  const int tid = threadIdx.x;
  const int lane = tid & 63, wave = tid >> 6;
  const int l16 = lane & 15, quad = lane >> 4;
  const int wm = (wave & 1) << 6, wn = (wave >> 1) << 6;
  const int bm = blockIdx.y, bn = blockIdx.x;

  f32x4 acc[4][4] = {};

  const int srow = tid >> 2;
  const int scol = (tid & 3) << 3;
  const size_t aoff = (size_t)(bm * 128 + srow) * K + scol;
  const uint16_t* Agh = (const uint16_t*)Ap + aoff;
  const float*    Agf = (const float*)Ap + aoff;
  const float*    Bg  = B + (size_t)(bn * 128 + srow) * K + scol;
  const size_t rstride = (size_t)64 * K;

  for (int k0 = 0; k0 < K; k0 += 32) {
    u16x8 a0, a1;
    if constexpr (A_BF16) {
      a0 = *(const u16x8*)Agh;
      a1 = *(const u16x8*)(Agh + rstride);
      Agh += 32;
    } else {
      a0 = ldcvt8(Agf);
      a1 = ldcvt8(Agf + rstride);
      Agf += 32;
    }
    u16x8 b0 = ldcvt8(Bg);
    u16x8 b1 = ldcvt8(Bg + rstride);
    Bg += 32;
    __syncthreads();
    *(u16x8*)&As[srow * PAD + scol] = a0;
    *(u16x8*)&As[(srow + 64) * PAD + scol] = a1;
    *(u16x8*)&Bs[srow * PAD + scol] = b0;
    *(u16x8*)&Bs[(srow + 64) * PAD + scol] = b1;
    __syncthreads();
    bf16x8 af[4], bfr[4];
#pragma unroll
    for (int i = 0; i < 4; i++) {
      af[i]  = __builtin_bit_cast(bf16x8, *(const u16x8*)&As[(wm + i * 16 + l16) * PAD + quad * 8]);
      bfr[i] = __builtin_bit_cast(bf16x8, *(const u16x8*)&Bs[(wn + i * 16 + l16) * PAD + quad * 8]);
    }
#pragma unroll
    for (int i = 0; i < 4; i++)
#pragma unroll
      for (int j = 0; j < 4; j++)
        acc[i][j] = __builtin_amdgcn_mfma_f32_16x16x32_bf16(af[i], bfr[j], acc[i][j], 0, 0, 0);
  }

  const int row0 = bm * 128 + wm + quad * 4;
  const int col0 = bn * 128 + wn + l16;
#pragma unroll
  for (int i = 0; i < 4; i++)
#pragma unroll
    for (int j = 0; j < 4; j++)
#pragma unroll
      for (int r = 0; r < 4; r++) {
        size_t idx = (size_t)(row0 + i * 16 + r) * N + (col0 + j * 16);
        if constexpr (OUT_BF16) ((uint16_t*)Cout)[idx] = f2bf(acc[i][j][r]);
        else                    ((float*)Cout)[idx]    = acc[i][j][r];
      }
}

// ---------------- RoPE + cache scatter + attention-buffer emit ----------------
__global__ __launch_bounds__(256) void rope_kernel(const uint16_t* __restrict__ xqkv,
    const float* __restrict__ cosf, const float* __restrict__ sinf,
    const int* __restrict__ pos,
    uint16_t* __restrict__ qb, uint16_t* __restrict__ kb, uint16_t* __restrict__ vb,
    float* __restrict__ ck, float* __restrict__ cv) {
  const float QS = 0.12751743f;  // 128^-0.5 * log2(e)
  const int s = blockIdx.x;
  const int e0 = (blockIdx.y * 256 + threadIdx.x) * 8;
  const int head = e0 >> 7;
  const int d0 = e0 & 127;
  u16x8 u = *(const u16x8*)(xqkv + (size_t)s * 6144 + e0);
  float x[8];
#pragma unroll
  for (int j = 0; j < 8; j++) x[j] = bf2f(u[j]);

  if (head < 40) {
    const int i0 = d0 >> 1;
    f32x4 c4 = *(const f32x4*)(cosf + (size_t)s * 64 + i0);
    f32x4 s4 = *(const f32x4*)(sinf + (size_t)s * 64 + i0);
    float o[8];
#pragma unroll
    for (int kk = 0; kk < 4; kk++) {
      float x1 = x[2 * kk], x2 = x[2 * kk + 1];
      o[2 * kk]     = x1 * c4[kk] - x2 * s4[kk];
      o[2 * kk + 1] = x1 * s4[kk] + x2 * c4[kk];
    }
    if (head < 32) {
      u16x8 ob;
#pragma unroll
      for (int j = 0; j < 8; j++) ob[j] = f2bf(o[j] * QS);
      *(u16x8*)(qb + (size_t)s * 4096 + head * 128 + d0) = ob;
    } else {
      u16x8 ob;
#pragma unroll
      for (int j = 0; j < 8; j++) ob[j] = f2bf(o[j]);
      int kvh = head - 32;
      *(u16x8*)(kb + ((size_t)kvh * 2048 + s) * 128 + d0) = ob;
      int p = pos[s];
      if ((unsigned)p < 4096u) {
        float* dst = ck + ((size_t)p * 8 + kvh) * 128 + d0;
#pragma unroll
        for (int j = 0; j < 8; j++) dst[j] = o[j];
      }
    }
  } else {
    int kvh = head - 40;
    *(u16x8*)(vb + ((size_t)kvh * 2048 + s) * 128 + d0) = u;
    int p = pos[s];
    if ((unsigned)p < 4096u) {
      float* dst = cv + ((size_t)p * 8 + kvh) * 128 + d0;
#pragma unroll
      for (int j = 0; j < 8; j++) dst[j] = x[j];
    }
  }
}

// ---------------- V transpose per kv head ----------------
__global__ __launch_bounds__(256) void vtrans_kernel(const uint16_t* __restrict__ vb,
                                                     uint16_t* __restrict__ vt) {
  __shared__ __align__(16) uint16_t t[32 * 72];
  const int h = blockIdx.z;
  const int s0 = blockIdx.x * 64, d0 = blockIdx.y * 32;
  const uint16_t* in = vb + (size_t)h * 2048 * 128;
  uint16_t* out = vt + (size_t)h * 128 * 2048;
  const int tid = threadIdx.x;
  {
    int r = tid >> 2, c8 = (tid & 3) * 8;
    u16x8 v = *(const u16x8*)(in + (size_t)(s0 + r) * 128 + d0 + c8);
#pragma unroll
    for (int j = 0; j < 8; j++) t[(c8 + j) * 72 + r] = v[j];
  }
  __syncthreads();
  {
    int r = tid >> 3, c8 = (tid & 7) * 8;
    u16x8 v = *(const u16x8*)&t[r * 72 + c8];
    *(u16x8*)(out + (size_t)(d0 + r) * 2048 + s0 + c8) = v;
  }
}

// ---------------- flash attention v3 (qtile-paired, base-2 softmax) ----------------
__global__ __launch_bounds__(256) void flash_kernel(const uint16_t* __restrict__ Qb,
    const uint16_t* __restrict__ Kb, const uint16_t* __restrict__ Vtb,
    uint16_t* __restrict__ Ob) {
  __shared__ __align__(16) uint16_t Ks[64 * 128];
  __shared__ __align__(16) uint16_t Vts[128 * 64];
  __shared__ __align__(16) uint16_t Ps[4][16 * 64];
  const int tid = threadIdx.x;
  const int lane = tid & 63, wave = tid >> 6;
  const int l16 = lane & 15, quad = lane >> 4;
  const int h = blockIdx.y, kvh = h >> 2;
  const uint16_t* Kg = Kb + (size_t)kvh * 2048 * 128;
  const uint16_t* Vg = Vtb + (size_t)kvh * 128 * 2048;

  u16x8 kreg[4], vreg[4];
  const int krr = tid >> 4, kcb = (tid & 15) * 16;
  const int vrr = tid >> 3, vcb = (tid & 7) * 16;

  for (int ph = 0; ph < 2; ph++) {
    const int qtile = ph ? (int)blockIdx.x : 31 - (int)blockIdx.x;
    const int qb = qtile * 64;
    const int nch = qtile + 1;
    const int qmax = qb + wave * 16 + 15;

    bf16x8 qf[4];
    {
      const uint16_t* Qg = Qb + (size_t)(qb + wave * 16 + l16) * 4096 + h * 128 + quad * 8;
#pragma unroll
      for (int dc = 0; dc < 4; dc++)
        qf[dc] = __builtin_bit_cast(bf16x8, *(const u16x8*)(Qg + dc * 32));
    }

    f32x4 oacc[8] = {};
    float m_run[4], l_run[4];
#pragma unroll
    for (int r = 0; r < 4; r++) { m_run[r] = -1e30f; l_run[r] = 0.f; }

#pragma unroll
    for (int i = 0; i < 4; i++)
      kreg[i] = *(const u16x8*)(Kg + (size_t)(krr + i * 16) * 128 + kcb / 2);
#pragma unroll
    for (int i = 0; i < 4; i++)
      vreg[i] = *(const u16x8*)(Vg + (size_t)(vrr + i * 32) * 2048 + vcb / 2);

    for (int ch = 0; ch < nch; ch++) {
      const int cb = ch * 64;
#pragma unroll
      for (int i = 0; i < 4; i++) {
        int r = krr + i * 16;
        *(u16x8*)((char*)Ks + r * 256 + (kcb ^ ((r & 7) << 4))) = kreg[i];
      }
#pragma unroll
      for (int i = 0; i < 4; i++) {
        int r = vrr + i * 32;
        *(u16x8*)((char*)Vts + r * 128 + (vcb ^ ((r & 7) << 4))) = vreg[i];
      }
      __syncthreads();

      if (ch + 1 < nch) {
        const int nb = cb + 64;
#pragma unroll
        for (int i = 0; i < 4; i++)
          kreg[i] = *(const u16x8*)(Kg + (size_t)(nb + krr + i * 16) * 128 + kcb / 2);
#pragma unroll
        for (int i = 0; i < 4; i++)
          vreg[i] = *(const u16x8*)(Vg + (size_t)(vrr + i * 32) * 2048 + nb + vcb / 2);
      }

      f32x4 sacc[4] = {};
      __builtin_amdgcn_s_setprio(1);
#pragma unroll
      for (int ni = 0; ni < 4; ni++) {
        if (cb + ni * 16 <= qmax) {
#pragma unroll
          for (int dc = 0; dc < 4; dc++) {
            int r = ni * 16 + l16;
            bf16x8 kf = __builtin_bit_cast(bf16x8,
                *(const u16x8*)((const char*)Ks + r * 256 + ((dc * 64 + quad * 16) ^ ((r & 7) << 4))));
            sacc[ni] = __builtin_amdgcn_mfma_f32_16x16x32_bf16(qf[dc], kf, sacc[ni], 0, 0, 0);
          }
        }
      }
      __builtin_amdgcn_s_setprio(0);

      float p[4][4], alpha[4];
#pragma unroll
      for (int reg = 0; reg < 4; reg++) {
        const int q = qb + wave * 16 + quad * 4 + reg;
        float mx = -1e30f;
#pragma unroll
        for (int ni = 0; ni < 4; ni++) {
          float sv = sacc[ni][reg];
          if (cb + ni * 16 + l16 > q) sv = -1e30f;
          p[ni][reg] = sv;
          mx = fmaxf(mx, sv);
        }
#pragma unroll
        for (int off = 8; off >= 1; off >>= 1)
          mx = fmaxf(mx, __shfl_xor(mx, off, 64));
        float mn = fmaxf(m_run[reg], mx);
        alpha[reg] = __builtin_amdgcn_exp2f(m_run[reg] - mn);
        m_run[reg] = mn;
        float rs = 0.f;
#pragma unroll
        for (int ni = 0; ni < 4; ni++) {
          float e = __builtin_amdgcn_exp2f(p[ni][reg] - mn);
          p[ni][reg] = e;
          rs += e;
        }
#pragma unroll
        for (int off = 8; off >= 1; off >>= 1)
          rs += __shfl_xor(rs, off, 64);
        l_run[reg] = l_run[reg] * alpha[reg] + rs;
      }

#pragma unroll
      for (int dt = 0; dt < 8; dt++)
#pragma unroll
        for (int reg = 0; reg < 4; reg++)
          oacc[dt][reg] *= alpha[reg];

      uint16_t* Pw = Ps[wave];
#pragma unroll
      for (int ni = 0; ni < 4; ni++)
#pragma unroll
        for (int reg = 0; reg < 4; reg++) {
          int r = quad * 4 + reg;
          *(uint16_t*)((char*)Pw + r * 128 + ((ni * 32 + l16 * 2) ^ ((r & 7) << 4))) =
              f2bf(p[ni][reg]);
        }

      __builtin_amdgcn_s_setprio(1);
#pragma unroll
      for (int kc = 0; kc < 2; kc++) {
        if (cb + kc * 32 <= qmax) {
          bf16x8 pf = __builtin_bit_cast(bf16x8,
              *(const u16x8*)((const char*)Pw + l16 * 128 + ((kc * 64 + quad * 16) ^ ((l16 & 7) << 4))));
#pragma unroll
          for (int dt = 0; dt < 8; dt++) {
            int r = dt * 16 + l16;
            bf16x8 vf = __builtin_bit_cast(bf16x8,
                *(const u16x8*)((const char*)Vts + r * 128 + ((kc * 64 + quad * 16) ^ ((r & 7) << 4))));
            oacc[dt] = __builtin_amdgcn_mfma_f32_16x16x32_bf16(pf, vf, oacc[dt], 0, 0, 0);
          }
        }
      }
      __builtin_amdgcn_s_setprio(0);

      __syncthreads();
    }

#pragma unroll
    for (int dt = 0; dt < 8; dt++)
#pragma unroll
      for (int reg = 0; reg < 4; reg++) {
        float o = oacc[dt][reg] / l_run[reg];
        int row = qb + wave * 16 + quad * 4 + reg;
        int col = h * 128 + dt * 16 + l16;
        Ob[(size_t)row * 4096 + col] = f2bf(o);
      }
  }
}

extern "C" void kernel_launch(void* const* d_in, const int* in_sizes, int n_in,
                              void* d_out, int out_size, void* d_ws, size_t ws_size,
                              hipStream_t stream) {
  const float* x     = (const float*)d_in[0];
  const float* cosf  = (const float*)d_in[1];
  const float* sinf  = (const float*)d_in[2];
  const int*   pos   = (const int*)d_in[3];
  const float* ck_in = (const float*)d_in[5];
  const float* cv_in = (const float*)d_in[6];
  const float* Wqkv  = (const float*)d_in[7];
  const float* Wo    = (const float*)d_in[8];

  float* out    = (float*)d_out;
  float* ck_out = out + (size_t)2048 * 4096;
  float* cv_out = ck_out + (size_t)4096 * 8 * 128;

  char* ws = (char*)d_ws;

  if (ws_size >= 104857600ull) {
    uint16_t* xqkv_bf = (uint16_t*)(ws);
    uint16_t* attn_bf = (uint16_t*)(ws);
    uint16_t* x_bf    = (uint16_t*)(ws + 25165824);
    uint16_t* q_bf    = (uint16_t*)(ws + 25165824);
    uint16_t* k_bf    = (uint16_t*)(ws + 41943040);
    uint16_t* v_bf    = (uint16_t*)(ws + 46137344);
    uint16_t* vt_bf   = (uint16_t*)(ws + 50331648);
    uint16_t* wq_bf   = (uint16_t*)(ws + 54525952);
    uint16_t* wo_bf   = (uint16_t*)(ws + 54525952);

    cast_kernel<<<4096, 256, 0, stream>>>(x, x_bf, 1048576);
    cast_kernel<<<12288, 256, 0, stream>>>(Wqkv, wq_bf, 3145728);

    bool ok256 = true;
    gemm256<1><<<dim3(24, 8, 1), 512, 0, stream>>>(x_bf, wq_bf, xqkv_bf, 2048, 6144, 4096, 4096);
    if (hipGetLastError() != hipSuccess) {
      ok256 = false;
      gemm_nt_bf16<1><<<dim3(48, 16), 256, 0, stream>>>(x_bf, wq_bf, xqkv_bf, 2048, 6144, 4096);
    }

    copy2_kernel<<<4096, 256, 0, stream>>>(ck_in, ck_out, cv_in, cv_out, 1048576);

    rope_kernel<<<dim3(2048, 3), 256, 0, stream>>>(xqkv_bf, cosf, sinf, pos,
                                                   q_bf, k_bf, v_bf, ck_out, cv_out);

    vtrans_kernel<<<dim3(32, 4, 8), 256, 0, stream>>>(v_bf, vt_bf);

    flash_kernel<<<dim3(16, 32), 256, 0, stream>>>(q_bf, k_bf, vt_bf, attn_bf);

    cast_kernel<<<8192, 256, 0, stream>>>(Wo, wo_bf, 2097152);

    if (ok256) {
      // split-K=2 Wo (one dispatch, 256 blocks) when ws has room for fp32 partials
      if (ws_size >= 155189248ull) {
        float* p0 = (float*)(ws + 88080384);
        float* p1 = p0 + (size_t)2048 * 4096;
        gemm256<0><<<dim3(16, 8, 2), 512, 0, stream>>>(attn_bf, wo_bf, p0, 2048, 4096, 4096, 2048);
        if (hipGetLastError() == hipSuccess) {
          add2_kernel<<<8192, 256, 0, stream>>>(p0, p1, out, 2097152);
        } else {
          gemm_nt_bf16<0><<<dim3(32, 16), 256, 0, stream>>>(attn_bf, wo_bf, out, 2048, 4096, 4096);
        }
      } else {
        gemm256<0><<<dim3(16, 8, 1), 512, 0, stream>>>(attn_bf, wo_bf, out, 2048, 4096, 4096, 4096);
        if (hipGetLastError() != hipSuccess)
          gemm_nt_bf16<0><<<dim3(32, 16), 256, 0, stream>>>(attn_bf, wo_bf, out, 2048, 4096, 4096);
      }
    } else {
      gemm_nt_bf16<0><<<dim3(32, 16), 256, 0, stream>>>(attn_bf, wo_bf, out, 2048, 4096, 4096);
    }
  } else {
    uint16_t* xqkv_bf = (uint16_t*)(ws);
    uint16_t* attn_bf = (uint16_t*)(ws);
    uint16_t* q_bf    = (uint16_t*)(ws + 25165824);
    uint16_t* k_bf    = (uint16_t*)(ws + 41943040);
    uint16_t* v_bf    = (uint16_t*)(ws + 46137344);
    uint16_t* vt_bf   = (uint16_t*)(ws + 50331648);

    gemm_bt<0, 1><<<dim3(48, 16), 256, 0, stream>>>(x, Wqkv, xqkv_bf, 2048, 6144, 4096);
    copy2_kernel<<<4096, 256, 0, stream>>>(ck_in, ck_out, cv_in, cv_out, 1048576);
    rope_kernel<<<dim3(2048, 3), 256, 0, stream>>>(xqkv_bf, cosf, sinf, pos,
                                                   q_bf, k_bf, v_bf, ck_out, cv_out);
    vtrans_kernel<<<dim3(32, 4, 8), 256, 0, stream>>>(v_bf, vt_bf);
    flash_kernel<<<dim3(16, 32), 256, 0, stream>>>(q_bf, k_bf, vt_bf, attn_bf);
    gemm_bt<1, 0><<<dim3(32, 16), 256, 0, stream>>>(attn_bf, Wo, out, 2048, 4096, 4096);
  }
}